// Round 9
// baseline (709.506 us; speedup 1.0000x reference)
//
#include <hip/hip_runtime.h>
#include <math.h>

#define NB    4        // graphs
#define NN    8192     // coarse nodes
#define MM    65536    // fine nodes
#define EE    131072   // edges
#define NPG   2048     // coarse per graph

typedef short short8 __attribute__((ext_vector_type(8)));
typedef float f32x4  __attribute__((ext_vector_type(4)));

static __device__ inline unsigned short f2b(float f) {
    unsigned u = __float_as_uint(f);
    u += 0x7fffu + ((u >> 16) & 1u);           // RNE
    return (unsigned short)(u >> 16);
}
static __device__ inline unsigned f2b_pack(float a, float b) {
    unsigned x = __float_as_uint(a); x += 0x7fffu + ((x >> 16) & 1u);
    unsigned y = __float_as_uint(b); y += 0x7fffu + ((y >> 16) & 1u);
    return (x >> 16) | (y & 0xffff0000u);
}
static __device__ inline short8 bc8(uint4 v) {
    union { uint4 u; short8 s; } c; c.u = v; return c.s;
}

// ---------------------------------------------------------------------------
// knn_interpolate (k=3), chunk-min two-phase scan (round-4 structure,
// verified -24us). Candidate transform computed inline during staging.
// 512 blocks x 512 thr; 128 fine nodes/block, 2 nodes/thread.
// ---------------------------------------------------------------------------
__global__ __launch_bounds__(512)
void k_knn(const float* __restrict__ pos, const float* __restrict__ pos_skip,
           const float* __restrict__ x, const float* __restrict__ x_skip,
           const int* __restrict__ batch_skip,
           float* __restrict__ h0, float* __restrict__ out_pos,
           float* __restrict__ out_batch)
{
    __shared__ float4 cp[2048];                      // 32 KB (-2x,-2y,-2z,|c|^2)
    __shared__ float  pk[8][128][3];                 // 12 KB per-slice top-3 chunk keys
    __shared__ int    chosen[128][3];                // 1.5 KB global top-3 chunk ids
    __shared__ unsigned long long fin[3][128][3];    // 9 KB per-chunk exact top-3
    __shared__ float  wFin[128][3];
    __shared__ int    iFin[128][3];

    int tid = threadIdx.x;
    int g = blockIdx.x >> 7;                         // 128 blocks per graph
    int cbase = g * NPG;
    int fbase = blockIdx.x * 128;
    int wave = tid >> 6;                             // 8 waves = 8 slices
    int lane = tid & 63;

    for (int c = tid; c < 2048; c += 512) {
        int cc = cbase + c;
        float px = pos[cc * 3 + 0];
        float py = pos[cc * 3 + 1];
        float pz = pos[cc * 3 + 2];
        cp[c] = make_float4(-2.f * px, -2.f * py, -2.f * pz,
                            px * px + py * py + pz * pz);
    }

    int nA = lane, nB = lane + 64;
    float fxA = pos_skip[(fbase + nA) * 3 + 0];
    float fyA = pos_skip[(fbase + nA) * 3 + 1];
    float fzA = pos_skip[(fbase + nA) * 3 + 2];
    float fxB = pos_skip[(fbase + nB) * 3 + 0];
    float fyB = pos_skip[(fbase + nB) * 3 + 1];
    float fzB = pos_skip[(fbase + nB) * 3 + 2];
    __syncthreads();

    const float4* cps = cp + wave * 256;
    float k0A = 3.4028235e38f, k1A = 3.4028235e38f, k2A = 3.4028235e38f;
    float k0B = 3.4028235e38f, k1B = 3.4028235e38f, k2B = 3.4028235e38f;
#pragma unroll
    for (int j = 0; j < 8; ++j) {
        float mA = 3.4028235e38f, mB = 3.4028235e38f;
#pragma unroll 8
        for (int i = 0; i < 32; ++i) {
            float4 cc = cps[j * 32 + i];             // wave-uniform broadcast read
            float dA = fmaf(cc.x, fxA, cc.w);        // |f|^2 dropped: rank-equiv
            dA = fmaf(cc.y, fyA, dA);
            dA = fmaf(cc.z, fzA, dA);
            mA = fminf(mA, dA);
            float dB = fmaf(cc.x, fxB, cc.w);
            dB = fmaf(cc.y, fyB, dB);
            dB = fmaf(cc.z, fzB, dB);
            mB = fminf(mB, dB);
        }
        unsigned cid = (unsigned)(wave * 8 + j);     // global chunk id [0,64)
        float keyA = __uint_as_float((__float_as_uint(mA) & 0xFFFFFFC0u) | cid);
        float tA = fmaxf(k1A, keyA);
        k2A = fminf(k2A, tA);
        k1A = __builtin_amdgcn_fmed3f(k0A, k1A, keyA);
        k0A = fminf(k0A, keyA);
        float keyB = __uint_as_float((__float_as_uint(mB) & 0xFFFFFFC0u) | cid);
        float tB = fmaxf(k1B, keyB);
        k2B = fminf(k2B, tB);
        k1B = __builtin_amdgcn_fmed3f(k0B, k1B, keyB);
        k0B = fminf(k0B, keyB);
    }
    pk[wave][nA][0] = k0A; pk[wave][nA][1] = k1A; pk[wave][nA][2] = k2A;
    pk[wave][nB][0] = k0B; pk[wave][nB][1] = k1B; pk[wave][nB][2] = k2B;
    __syncthreads();

    // global top-3 chunks per node (24 keys; ids distinct by construction)
    if (tid < 128) {
        int n = tid;
        float m0 = 3.4028235e38f, m1 = 3.4028235e38f, m2 = 3.4028235e38f;
#pragma unroll
        for (int s = 0; s < 8; ++s)
#pragma unroll
            for (int r = 0; r < 3; ++r) {
                float k = pk[s][n][r];
                float t = fmaxf(m1, k);
                m2 = fminf(m2, t);
                m1 = __builtin_amdgcn_fmed3f(m0, m1, k);
                m0 = fminf(m0, k);
            }
        chosen[n][0] = (int)(__float_as_uint(m0) & 63u);
        chosen[n][1] = (int)(__float_as_uint(m1) & 63u);
        chosen[n][2] = (int)(__float_as_uint(m2) & 63u);
    }
    __syncthreads();

    // rescan the 3 chosen chunks exactly (threads 0..383: node = tid&127,
    // chunk slot j = tid>>7); lane-rotated gather breaks bank aliasing.
    if ((tid >> 7) < 3) {
        int n = tid & 127;
        int j = tid >> 7;
        int cid = chosen[n][j];
        int fn = fbase + n;
        float gx = pos_skip[fn * 3 + 0], gy = pos_skip[fn * 3 + 1], gz = pos_skip[fn * 3 + 2];
        float gq = gx * gx + gy * gy + gz * gz;
        unsigned long long m0 = ~0ull, m1 = ~0ull, m2 = ~0ull;
#pragma unroll 4
        for (int i = 0; i < 32; ++i) {
            int ii = (i + lane) & 31;
            float4 cc = cp[cid * 32 + ii];
            float d = gq + cc.w;
            d = fmaf(cc.x, gx, d);
            d = fmaf(cc.y, gy, d);
            d = fmaf(cc.z, gz, d);
            d = fmaxf(d, 0.f);
            unsigned c = (unsigned)(cbase + cid * 32 + ii);
            unsigned long long kk = ((unsigned long long)__float_as_uint(d) << 32) | c;
            unsigned long long t1 = m0 > kk ? m0 : kk; m0 = m0 < kk ? m0 : kk;
            unsigned long long t2 = m1 > t1 ? m1 : t1; m1 = m1 < t1 ? m1 : t1;
            m2 = m2 < t2 ? m2 : t2;
        }
        fin[j][n][0] = m0; fin[j][n][1] = m1; fin[j][n][2] = m2;
    }
    __syncthreads();

    if (tid < 128) {
        int n = tid;
        int fn = fbase + n;
        unsigned long long m0 = ~0ull, m1 = ~0ull, m2 = ~0ull;
#pragma unroll
        for (int j = 0; j < 3; ++j)
#pragma unroll
            for (int r = 0; r < 3; ++r) {
                unsigned long long kk = fin[j][n][r];
                unsigned long long t1 = m0 > kk ? m0 : kk; m0 = m0 < kk ? m0 : kk;
                unsigned long long t2 = m1 > t1 ? m1 : t1; m1 = m1 < t1 ? m1 : t1;
                m2 = m2 < t2 ? m2 : t2;
            }
        float d0 = __uint_as_float((unsigned)(m0 >> 32));
        float d1 = __uint_as_float((unsigned)(m1 >> 32));
        float d2 = __uint_as_float((unsigned)(m2 >> 32));
        float w0 = 1.f / fmaxf(d0, 1e-16f);
        float w1 = 1.f / fmaxf(d1, 1e-16f);
        float w2 = 1.f / fmaxf(d2, 1e-16f);
        float inv = 1.f / (w0 + w1 + w2);
        wFin[n][0] = w0 * inv; wFin[n][1] = w1 * inv; wFin[n][2] = w2 * inv;
        iFin[n][0] = (int)(m0 & 0xffffffffull);
        iFin[n][1] = (int)(m1 & 0xffffffffull);
        iFin[n][2] = (int)(m2 & 0xffffffffull);
        float gx = pos_skip[fn * 3 + 0], gy = pos_skip[fn * 3 + 1], gz = pos_skip[fn * 3 + 2];
        out_pos[fn * 3 + 0] = gx; out_pos[fn * 3 + 1] = gy; out_pos[fn * 3 + 2] = gz;
        out_batch[fn] = (float)batch_skip[fn];
    }
    __syncthreads();

    int n2 = tid >> 2, part = tid & 3;               // 512 thr -> 128 nodes x 4
    int f2 = fbase + n2;
    float4* h04 = (float4*)(h0 + (size_t)f2 * 32);
    if (part < 2) {
        const float4* x4 = (const float4*)x;
        float w0 = wFin[n2][0], w1 = wFin[n2][1], w2 = wFin[n2][2];
        int a0 = iFin[n2][0] * 4, a1 = iFin[n2][1] * 4, a2 = iFin[n2][2] * 4;
#pragma unroll
        for (int j = 0; j < 2; ++j) {
            int cj = part * 2 + j;
            float4 v0 = x4[a0 + cj], v1 = x4[a1 + cj], v2 = x4[a2 + cj];
            float4 r;
            r.x = w0 * v0.x + w1 * v1.x + w2 * v2.x;
            r.y = w0 * v0.y + w1 * v1.y + w2 * v2.y;
            r.z = w0 * v0.z + w1 * v1.z + w2 * v2.z;
            r.w = w0 * v0.w + w1 * v1.w + w2 * v2.w;
            h04[cj] = r;
        }
    } else {
        const float4* xs4 = (const float4*)x_skip;
#pragma unroll
        for (int j = 0; j < 2; ++j) {
            int cj = (part - 2) * 2 + j;
            h04[4 + cj] = xs4[f2 * 4 + cj];
        }
    }
}

// ---------------------------------------------------------------------------
// token prep 1: Kt/Vt = gt @ W^T + b + pe   -> KtVt [B][2][16][64]
// ---------------------------------------------------------------------------
__global__ __launch_bounds__(128)
void k_tokens1(const float* __restrict__ gt,
               const float* __restrict__ Wk_w, const float* __restrict__ Wk_b,
               const float* __restrict__ Wv_w, const float* __restrict__ Wv_b,
               float* __restrict__ KtVt)
{
    int b = blockIdx.x >> 4;
    int t = blockIdx.x & 15;
    int which = threadIdx.x >> 6;
    int d = threadIdx.x & 63;
    const float* W = which ? Wv_w : Wk_w;
    const float* bias = which ? Wv_b : Wk_b;
    const float4* row = (const float4*)(gt + (size_t)(b * 16 + t) * 1024);
    const float4* wr = (const float4*)(W + (size_t)d * 1024);
    float acc = 0.f;
    for (int c = 0; c < 256; ++c) {
        float4 a = row[c], w = wr[c];
        acc += a.x * w.x; acc += a.y * w.y; acc += a.z * w.z; acc += a.w * w.w;
    }
    int i2 = d >> 1;
    float dv = expf((float)(2 * i2) * (-0.14391156831212787f)); // -ln(10000)/64
    float ang = (float)t * dv;
    float pe = (d & 1) ? cosf(ang) : sinf(ang);
    KtVt[((size_t)(b * 2 + which) * 16 + t) * 64 + d] = acc + bias[d] + pe;
}

// ---------------------------------------------------------------------------
// token prep 2 (per graph): k/v head proj; V2 = out_w-folded v heads into LDS;
// emits Mfold[g][th=t*4+h][4] and v2f[g] (V2^T, bf16 A-frag layout).
// ---------------------------------------------------------------------------
__global__ __launch_bounds__(256)
void k_tokens2(const float* __restrict__ KtVt,
               const float* __restrict__ in_proj_w, const float* __restrict__ in_proj_b,
               const float* __restrict__ out_w,
               const float* __restrict__ Wq_w, const float* __restrict__ Wq_b,
               float* __restrict__ Mfold, uint4* __restrict__ v2fG)
{
    int b = blockIdx.x;
    int tid = threadIdx.x;
    __shared__ float KtL[1024], VtL[1024], vv[1024], kproj[1024];
    __shared__ float v2L[4096];
    __shared__ float qWs[192], qbs[64];
    for (int idx = tid; idx < 1024; idx += 256) {
        KtL[idx] = KtVt[(size_t)(b * 2 + 0) * 1024 + idx];
        VtL[idx] = KtVt[(size_t)(b * 2 + 1) * 1024 + idx];
    }
    __syncthreads();
    for (int idx = tid; idx < 2048; idx += 256) {
        int which = idx >> 10; int td = idx & 1023; int t = td >> 6; int j = td & 63;
        int r = (which ? 128 : 64) + j;
        const float* w = in_proj_w + (size_t)r * 64;
        const float* src = which ? VtL : KtL;
        float acc = in_proj_b[r];
#pragma unroll 8
        for (int dd = 0; dd < 64; ++dd) acc += src[t * 64 + dd] * w[dd];
        if (which) vv[t * 64 + j] = acc;
        else kproj[t * 64 + j] = acc;
    }
    for (int idx = tid; idx < 192; idx += 256) {
        int c = idx >> 6; int j = idx & 63;
        float acc = 0.f;
        for (int dd = 0; dd < 64; ++dd) acc += in_proj_w[(size_t)j * 64 + dd] * Wq_w[dd * 3 + c];
        qWs[c * 64 + j] = acc;
    }
    for (int j = tid; j < 64; j += 256) {
        float acc = in_proj_b[j];
        for (int dd = 0; dd < 64; ++dd) acc += in_proj_w[(size_t)j * 64 + dd] * Wq_b[dd];
        qbs[j] = acc;
    }
    __syncthreads();
    for (int idx = tid; idx < 4096; idx += 256) {
        int jo = idx & 63; int th2 = idx >> 6; int h = th2 & 3; int t = th2 >> 2;
        float acc = 0.f;
#pragma unroll
        for (int dd = 0; dd < 16; ++dd)
            acc += vv[t * 64 + h * 16 + dd] * out_w[(size_t)jo * 64 + h * 16 + dd];
        v2L[(t * 4 + h) * 64 + jo] = acc;
    }
    {
        int th = tid >> 2, c = tid & 3;
        int t = th >> 2, h = th & 3;
        float acc = 0.f;
#pragma unroll
        for (int dd = h * 16; dd < h * 16 + 16; ++dd) {
            float w = (c == 0) ? qWs[dd] : (c == 1) ? qWs[64 + dd]
                    : (c == 2) ? qWs[128 + dd] : qbs[dd];
            acc += w * kproj[t * 64 + dd];
        }
        Mfold[((size_t)b * 64 + th) * 4 + c] = 0.25f * acc;
    }
    __syncthreads();
    for (int it = tid; it < 512; it += 256) {
        int lane = it & 63, fi = it >> 6;
        int mi = fi >> 1, step = fi & 1;
        int outd = mi * 16 + (lane & 15);
        int th0 = step * 32 + (lane >> 4) * 8;
        uint4 v;
        v.x = f2b_pack(v2L[(th0 + 0) * 64 + outd], v2L[(th0 + 1) * 64 + outd]);
        v.y = f2b_pack(v2L[(th0 + 2) * 64 + outd], v2L[(th0 + 3) * 64 + outd]);
        v.z = f2b_pack(v2L[(th0 + 4) * 64 + outd], v2L[(th0 + 5) * 64 + outd]);
        v.w = f2b_pack(v2L[(th0 + 6) * 64 + outd], v2L[(th0 + 7) * 64 + outd]);
        v2fG[((size_t)b * 8 + fi) * 64 + lane] = v;
    }
}

// ---------------------------------------------------------------------------
// per-edge cross attention, MFMA PV (unchanged)
// ---------------------------------------------------------------------------
__global__ __launch_bounds__(256)
void k_edge_attn(const float* __restrict__ ps, const int* __restrict__ ei,
                 const float* __restrict__ Mfold, const uint4* __restrict__ v2f,
                 const float* __restrict__ ob,
                 unsigned short* __restrict__ Pf, float* __restrict__ cnt)
{
    __shared__ unsigned attL[4 * 64 * 34];     // 34.8 KB; per-wave 64x34-dword slab
    int tid = threadIdx.x;
    int wave = tid >> 6, lane = tid & 63, q = lane >> 4, c15 = lane & 15;
    int g = blockIdx.x >> 7;                   // 128 blocks per graph
    int e = blockIdx.x * 256 + tid;
    int s = ei[e], d = ei[EE + e];
    atomicAdd(&cnt[d], 1.f);
    float sx = ps[s * 3], sy = ps[s * 3 + 1], sz = ps[s * 3 + 2];
    float dx = ps[d * 3], dy = ps[d * 3 + 1], dz = ps[d * 3 + 2];
    float px = dx - sx, py = dy - sy, pz = dz - sz;
    float ex = 0.5f * (dx + sx), ey = 0.5f * (dy + sy), ez = 0.5f * (dz + sz);

    const float4* Mg = (const float4*)Mfold + (size_t)g * 64;
    float sc[64];
#pragma unroll
    for (int th = 0; th < 64; ++th) {
        float4 m = Mg[th];
        sc[th] = ex * m.x + ey * m.y + ez * m.z + m.w;
    }
#pragma unroll
    for (int h = 0; h < 4; ++h) {
        float mx = sc[h];
#pragma unroll
        for (int t = 1; t < 16; ++t) mx = fmaxf(mx, sc[t * 4 + h]);
        float ssum = 0.f;
#pragma unroll
        for (int t = 0; t < 16; ++t) {
            float eo = expf(sc[t * 4 + h] - mx);
            sc[t * 4 + h] = eo; ssum += eo;
        }
        float inv = 1.f / ssum;
#pragma unroll
        for (int t = 0; t < 16; ++t) sc[t * 4 + h] *= inv;
    }
    unsigned* slab = attL + wave * 64 * 34;
#pragma unroll
    for (int k = 0; k < 16; ++k) {
        uint2 v;
        v.x = f2b_pack(sc[4 * k + 0], sc[4 * k + 1]);
        v.y = f2b_pack(sc[4 * k + 2], sc[4 * k + 3]);
        *(uint2*)&slab[lane * 34 + 2 * k] = v;
    }
    __syncthreads();

    uint4 v2a[4][2];
#pragma unroll
    for (int mi = 0; mi < 4; ++mi)
#pragma unroll
        for (int st = 0; st < 2; ++st)
            v2a[mi][st] = v2f[((size_t)g * 8 + mi * 2 + st) * 64 + lane];

    f32x4 acc[4][4];
#pragma unroll
    for (int mi = 0; mi < 4; ++mi)
#pragma unroll
        for (int nt = 0; nt < 4; ++nt) acc[mi][nt] = (f32x4){0.f, 0.f, 0.f, 0.f};

#pragma unroll
    for (int nt = 0; nt < 4; ++nt) {
        const unsigned* rb = &slab[(nt * 16 + c15) * 34];
        uint4 b0 = *(const uint4*)&rb[q * 4];
        uint4 b1 = *(const uint4*)&rb[16 + q * 4];
#pragma unroll
        for (int mi = 0; mi < 4; ++mi) {
            acc[mi][nt] = __builtin_amdgcn_mfma_f32_16x16x32_bf16(bc8(v2a[mi][0]), bc8(b0), acc[mi][nt], 0, 0, 0);
            acc[mi][nt] = __builtin_amdgcn_mfma_f32_16x16x32_bf16(bc8(v2a[mi][1]), bc8(b1), acc[mi][nt], 0, 0, 0);
        }
    }
    __syncthreads();

    float4 obv[4];
#pragma unroll
    for (int mi = 0; mi < 4; ++mi) obv[mi] = *(const float4*)(ob + mi * 16 + q * 4);
#pragma unroll
    for (int mi = 0; mi < 4; ++mi)
#pragma unroll
        for (int nt = 0; nt < 4; ++nt) {
            f32x4 a = acc[mi][nt];
            uint2 v;
            v.x = f2b_pack(a[0] + obv[mi].x, a[1] + obv[mi].y);
            v.y = f2b_pack(a[2] + obv[mi].z, a[3] + obv[mi].w);
            *(uint2*)&slab[(nt * 16 + c15) * 34 + mi * 8 + q * 2] = v;
        }
    __syncthreads();

    uint4* Pf4 = (uint4*)Pf;
#pragma unroll
    for (int et = 0; et < 4; ++et) {
        int etg = blockIdx.x * 16 + wave * 4 + et;
#pragma unroll
        for (int st = 0; st < 2; ++st) {
            uint4 w = *(const uint4*)&slab[(et * 16 + c15) * 34 + st * 16 + q * 4];
            Pf4[((size_t)etg * 3 + st) * 64 + lane] = w;
        }
    }
    int et2 = e >> 4, eL = e & 15;
    size_t tb = ((size_t)(et2 * 3 + 2) * 64 + 0 * 16 + eL) * 8;
    uint2 t0; t0.x = f2b_pack(px, py); t0.y = f2b_pack(pz, 1.0f);
    *(uint2*)(Pf + tb) = t0;
    uint2 z2; z2.x = 0u; z2.y = 0u;
    *(uint2*)(Pf + tb + 4) = z2;
#pragma unroll
    for (int quad = 1; quad < 4; ++quad) {
        size_t zb = ((size_t)(et2 * 3 + 2) * 64 + quad * 16 + eL) * 8;
        uint4 z4; z4.x = 0u; z4.y = 0u; z4.z = 0u; z4.w = 0u;
        *(uint4*)(Pf + zb) = z4;
    }
}

// ---------------------------------------------------------------------------
// fused repack of all 3 layers' nn_w/nn_b -> bf16 B-fragment streams
// ---------------------------------------------------------------------------
static __device__ inline void repack_one(const float* __restrict__ nw,
                                         const float* __restrict__ nb,
                                         unsigned short* __restrict__ Wf, int idx)
{
    int jj = idx & 7;
    int lane = (idx >> 3) & 63;
    int rest = idx >> 9;
    int s = rest % 3;
    int jt = rest / 3;
    int j = jt * 16 + (lane & 15);
    int k = s * 32 + (lane >> 4) * 8 + jj;
    float v;
    if (k < 64)       v = nw[(size_t)j * 67 + 3 + k];
    else if (k < 67)  v = nw[(size_t)j * 67 + (k - 64)];
    else if (k == 67) v = nb[j];
    else              v = 0.f;
    Wf[idx] = f2b(v);
}

__global__ __launch_bounds__(256)
void k_repackAll(const float* __restrict__ nw0, const float* __restrict__ nb0,
                 const float* __restrict__ nw1, const float* __restrict__ nb1,
                 const float* __restrict__ nw2, const float* __restrict__ nb2,
                 unsigned short* __restrict__ Wf0, unsigned short* __restrict__ Wf1,
                 unsigned short* __restrict__ Wf2)
{
    int idx = blockIdx.x * 256 + threadIdx.x;
    if (idx < 98304)        repack_one(nw0, nb0, Wf0, idx);
    else if (idx < 196608)  repack_one(nw1, nb1, Wf1, idx - 98304);
    else                    repack_one(nw2, nb2, Wf2, idx - 196608);
}

// ---------------------------------------------------------------------------
// MFMA edge pass. R4-proven inner loop (hL[row][36], hv2 float2 batch, scalar
// epilogue), restructured to 64 edges/block, grid EE/64 = 2048: the 4 waves
// of a block split the i-reduction (CO=32: ig=wave>>1 i-half x half=wave&1
// col-half; CO=16: 4-way i-split) and combine partials in LDS before ONE
// atomic per output element -- same atomic volume as R4 (R8 lesson: block-
// split i doubled atomics -> 157MB writes -> 2.2x regression). Doubles
// waves/CU 16 -> 32 for the latency-bound loop (R6/R7 counters).
// ---------------------------------------------------------------------------
template<int CO>
__global__ __launch_bounds__(256, 8)
void k_conv_mfma(const uint4* __restrict__ Pf, const float* __restrict__ hin,
                 const int* __restrict__ ei, const uint4* __restrict__ Wf,
                 float* __restrict__ aggr)
{
    __shared__ float hL[64 * 36];              // 9.2 KB
    __shared__ int sL[64];
    __shared__ int dL[64];
    constexpr int REDSZ = (CO == 16) ? 3 * 64 * 17 : 2 * 64 * 17;
    __shared__ float red[REDSZ];               // 8.7 / 13.1 KB

    int tid = threadIdx.x;
    int e0 = blockIdx.x * 64;
    if (tid < 64)       sL[tid] = ei[e0 + tid];
    else if (tid < 128) dL[tid - 64] = ei[EE + e0 + (tid - 64)];
    __syncthreads();
    for (int idx = tid; idx < 512; idx += 256) {
        int row = idx >> 3, c = idx & 7;
        const float4* hr = (const float4*)(hin + (size_t)sL[row] * 32);
        *(float4*)&hL[row * 36 + c * 4] = hr[c];
    }
    __syncthreads();

    int wave = tid >> 6, lane = tid & 63, quad = lane >> 4, col = lane & 15;
    int half = wave & 1;

    uint4 a[4][3];
    int et0 = blockIdx.x * 4;
#pragma unroll
    for (int st = 0; st < 4; ++st)
#pragma unroll
        for (int s = 0; s < 3; ++s)
            a[st][s] = Pf[((size_t)(et0 + st) * 3 + s) * 64 + lane];

    float msg[4][4];
#pragma unroll
    for (int st = 0; st < 4; ++st)
#pragma unroll
        for (int r = 0; r < 4; ++r) msg[st][r] = 0.f;

    // i ranges: CO=32 -> wave=(ig,half): i in [ig*16,+16), jt=i*2+half;
    //           CO=16 -> i in [wave*8,+8), jt=i.
    int ibase = (CO == 32) ? (wave >> 1) * 16 : wave * 8;
    constexpr int NI2 = (CO == 32) ? 8 : 4;    // i-pairs per wave

    for (int i2 = 0; i2 < NI2; ++i2) {
        float2 hv2[4][4];
#pragma unroll
        for (int st = 0; st < 4; ++st)
#pragma unroll
            for (int r = 0; r < 4; ++r)
                hv2[st][r] = *(const float2*)&hL[(st * 16 + quad * 4 + r) * 36
                                                 + ibase + i2 * 2];
#pragma unroll
        for (int ii = 0; ii < 2; ++ii) {
            int i = ibase + i2 * 2 + ii;
            int jt = (CO == 32) ? (i * 2 + half) : i;
            uint4 b0 = Wf[((size_t)jt * 3 + 0) * 64 + lane];
            uint4 b1 = Wf[((size_t)jt * 3 + 1) * 64 + lane];
            uint4 b2 = Wf[((size_t)jt * 3 + 2) * 64 + lane];
#pragma unroll
            for (int st = 0; st < 4; ++st) {
                f32x4 c = {0.f, 0.f, 0.f, 0.f};
                c = __builtin_amdgcn_mfma_f32_16x16x32_bf16(bc8(a[st][0]), bc8(b0), c, 0, 0, 0);
                c = __builtin_amdgcn_mfma_f32_16x16x32_bf16(bc8(a[st][1]), bc8(b1), c, 0, 0, 0);
                c = __builtin_amdgcn_mfma_f32_16x16x32_bf16(bc8(a[st][2]), bc8(b2), c, 0, 0, 0);
#pragma unroll
                for (int r = 0; r < 4; ++r) {
                    float hv = ii ? hv2[st][r].y : hv2[st][r].x;
                    msg[st][r] += hv * fmaxf(c[r], 0.f);
                }
            }
        }
    }

    if (CO == 32) {
        if (wave >= 2) {                       // ig=1: publish partials
#pragma unroll
            for (int st = 0; st < 4; ++st)
#pragma unroll
                for (int r = 0; r < 4; ++r)
                    red[(half * 64 + lane) * 17 + st * 4 + r] = msg[st][r];
        }
        __syncthreads();
        if (wave < 2) {                        // ig=0: combine + single atomic
#pragma unroll
            for (int st = 0; st < 4; ++st)
#pragma unroll
                for (int r = 0; r < 4; ++r) {
                    float m = msg[st][r] + red[(half * 64 + lane) * 17 + st * 4 + r];
                    int dv = dL[st * 16 + quad * 4 + r];
                    atomicAdd(&aggr[(size_t)dv * 32 + half * 16 + col], m);
                }
        }
    } else {
        if (wave > 0) {
#pragma unroll
            for (int st = 0; st < 4; ++st)
#pragma unroll
                for (int r = 0; r < 4; ++r)
                    red[((wave - 1) * 64 + lane) * 17 + st * 4 + r] = msg[st][r];
        }
        __syncthreads();
        if (wave == 0) {
#pragma unroll
            for (int st = 0; st < 4; ++st)
#pragma unroll
                for (int r = 0; r < 4; ++r) {
                    float m = msg[st][r]
                            + red[(0 * 64 + lane) * 17 + st * 4 + r]
                            + red[(1 * 64 + lane) * 17 + st * 4 + r]
                            + red[(2 * 64 + lane) * 17 + st * 4 + r];
                    int dv = dL[st * 16 + quad * 4 + r];
                    atomicAdd(&aggr[(size_t)dv * 16 + col], m);
                }
        }
    }
}

// ---------------------------------------------------------------------------
// node update: h' = relu(aggr/cnt + h @ root + bias); zeroes aggr for the
// next layer's atomic pass.
// ---------------------------------------------------------------------------
template<int CO>
__global__ __launch_bounds__(256)
void k_update(float* __restrict__ aggr, const float* __restrict__ cnt,
              const float* __restrict__ hin, const float* __restrict__ root,
              const float* __restrict__ bias, float* __restrict__ hout)
{
    __shared__ float rL[32 * CO];
    __shared__ float bL[CO];
    int tid = threadIdx.x;
    for (int idx = tid; idx < 32 * CO; idx += 256) rL[idx] = root[idx];
    if (tid < CO) bL[tid] = bias[tid];
    __syncthreads();
    int gid = blockIdx.x * 256 + tid;
    int v = gid / CO;
    int o = gid % CO;
    float acc = aggr[gid] / fmaxf(cnt[v], 1.f) + bL[o];
    aggr[gid] = 0.f;                    // prep next layer's scatter
    const float* hr = hin + (size_t)v * 32;
#pragma unroll
    for (int i = 0; i < 32; ++i) acc += hr[i] * rL[i * CO + o];
    hout[gid] = fmaxf(acc, 0.f);
}

// ---------------------------------------------------------------------------
extern "C" void kernel_launch(void* const* d_in, const int* in_sizes, int n_in,
                              void* d_out, int out_size, void* d_ws, size_t ws_size,
                              hipStream_t stream)
{
    const float* x          = (const float*)d_in[0];
    const float* pos        = (const float*)d_in[1];
    const float* x_skip     = (const float*)d_in[3];
    const float* pos_skip   = (const float*)d_in[4];
    const int*   batch_skip = (const int*)  d_in[5];
    const int*   ei         = (const int*)  d_in[6];
    const float* gt         = (const float*)d_in[7];
    const float* Wq_w       = (const float*)d_in[8];
    const float* Wq_b       = (const float*)d_in[9];
    const float* Wk_w       = (const float*)d_in[10];
    const float* Wk_b       = (const float*)d_in[11];
    const float* Wv_w       = (const float*)d_in[12];
    const float* Wv_b       = (const float*)d_in[13];
    const float* in_proj_w  = (const float*)d_in[14];
    const float* in_proj_b  = (const float*)d_in[15];
    const float* out_w      = (const float*)d_in[16];
    const float* out_b      = (const float*)d_in[17];
    const float* nn_w0 = (const float*)d_in[18]; const float* nn_b0 = (const float*)d_in[19];
    const float* root0 = (const float*)d_in[20]; const float* bias0 = (const float*)d_in[21];
    const float* nn_w1 = (const float*)d_in[22]; const float* nn_b1 = (const float*)d_in[23];
    const float* root1 = (const float*)d_in[24]; const float* bias1 = (const float*)d_in[25];
    const float* nn_w2 = (const float*)d_in[26]; const float* nn_b2 = (const float*)d_in[27];
    const float* root2 = (const float*)d_in[28]; const float* bias2 = (const float*)d_in[29];

    char* wsb = (char*)d_ws;
    size_t off = 0;
    auto carve = [&](size_t bytes) { char* p = wsb + off; off += (bytes + 255) & ~(size_t)255; return p; };
    float* aggr = (float*)carve((size_t)MM * 32 * 4);   // aggr then cnt: one memset
    float* cnt  = (float*)carve((size_t)MM * 4);
    float* hA   = (float*)carve((size_t)MM * 32 * 4);
    float* hB   = (float*)carve((size_t)MM * 32 * 4);
    unsigned short* Pf  = (unsigned short*)carve((size_t)EE * 96 * 2);
    unsigned short* Wf0 = (unsigned short*)carve((size_t)1024 * 96 * 2);
    unsigned short* Wf1 = (unsigned short*)carve((size_t)1024 * 96 * 2);
    unsigned short* Wf2 = (unsigned short*)carve((size_t)512 * 96 * 2);
    float* Mfold = (float*)carve((size_t)NB * 64 * 4 * 4);
    uint4* v2f   = (uint4*)carve((size_t)NB * 8 * 64 * 16);
    float* KtVt  = (float*)carve((size_t)NB * 2 * 16 * 64 * 4);

    float* h_final   = (float*)d_out;                 // [M,16]
    float* out_pos   = (float*)d_out + (size_t)MM * 16;
    float* out_batch = (float*)d_out + (size_t)MM * 19;

    // one memset covers aggr (MM*32) + cnt (MM) — adjacent carves
    hipMemsetAsync(aggr, 0, ((size_t)MM * 32 + MM) * sizeof(float), stream);

    k_knn<<<MM / 128, 512, 0, stream>>>(pos, pos_skip, x, x_skip, batch_skip,
                                        hA, out_pos, out_batch);
    k_tokens1<<<64, 128, 0, stream>>>(gt, Wk_w, Wk_b, Wv_w, Wv_b, KtVt);
    k_tokens2<<<NB, 256, 0, stream>>>(KtVt, in_proj_w, in_proj_b, out_w, Wq_w, Wq_b,
                                      Mfold, v2f);
    k_edge_attn<<<EE / 256, 256, 0, stream>>>(pos_skip, ei, Mfold, v2f, out_b,
                                              Pf, cnt);
    k_repackAll<<<960, 256, 0, stream>>>(nn_w0, nn_b0, nn_w1, nn_b1, nn_w2, nn_b2,
                                         Wf0, Wf1, Wf2);

    // layer 0: hA -> hB   (update zeroes aggr for layer 1)
    k_conv_mfma<32><<<EE / 64, 256, 0, stream>>>((const uint4*)Pf, hA, ei, (const uint4*)Wf0, aggr);
    k_update<32><<<(MM * 32) / 256, 256, 0, stream>>>(aggr, cnt, hA, root0, bias0, hB);
    // layer 1: hB -> hA   (update zeroes aggr for layer 2)
    k_conv_mfma<32><<<EE / 64, 256, 0, stream>>>((const uint4*)Pf, hB, ei, (const uint4*)Wf1, aggr);
    k_update<32><<<(MM * 32) / 256, 256, 0, stream>>>(aggr, cnt, hB, root1, bias1, hA);
    // layer 2: hA -> d_out
    k_conv_mfma<16><<<EE / 64, 256, 0, stream>>>((const uint4*)Pf, hA, ei, (const uint4*)Wf2, aggr);
    k_update<16><<<(MM * 16) / 256, 256, 0, stream>>>(aggr, cnt, hA, root2, bias2, h_final);
}

// Round 10
// 456.587 us; speedup vs baseline: 1.5539x; 1.5539x over previous
//
#include <hip/hip_runtime.h>
#include <math.h>

#define NB    4        // graphs
#define NN    8192     // coarse nodes
#define MM    65536    // fine nodes
#define EE    131072   // edges
#define NPG   2048     // coarse per graph

typedef short short8 __attribute__((ext_vector_type(8)));
typedef float f32x4  __attribute__((ext_vector_type(4)));

static __device__ inline unsigned short f2b(float f) {
    unsigned u = __float_as_uint(f);
    u += 0x7fffu + ((u >> 16) & 1u);           // RNE
    return (unsigned short)(u >> 16);
}
static __device__ inline unsigned f2b_pack(float a, float b) {
    unsigned x = __float_as_uint(a); x += 0x7fffu + ((x >> 16) & 1u);
    unsigned y = __float_as_uint(b); y += 0x7fffu + ((y >> 16) & 1u);
    return (x >> 16) | (y & 0xffff0000u);
}
static __device__ inline short8 bc8(uint4 v) {
    union { uint4 u; short8 s; } c; c.u = v; return c.s;
}

// ---------------------------------------------------------------------------
// knn_interpolate (k=3), chunk-min two-phase scan (round-4 structure,
// verified -24us). Candidate transform computed inline during staging.
// 512 blocks x 512 thr; 128 fine nodes/block, 2 nodes/thread.
// ---------------------------------------------------------------------------
__global__ __launch_bounds__(512)
void k_knn(const float* __restrict__ pos, const float* __restrict__ pos_skip,
           const float* __restrict__ x, const float* __restrict__ x_skip,
           const int* __restrict__ batch_skip,
           float* __restrict__ h0, float* __restrict__ out_pos,
           float* __restrict__ out_batch)
{
    __shared__ float4 cp[2048];                      // 32 KB (-2x,-2y,-2z,|c|^2)
    __shared__ float  pk[8][128][3];                 // 12 KB per-slice top-3 chunk keys
    __shared__ int    chosen[128][3];                // 1.5 KB global top-3 chunk ids
    __shared__ unsigned long long fin[3][128][3];    // 9 KB per-chunk exact top-3
    __shared__ float  wFin[128][3];
    __shared__ int    iFin[128][3];

    int tid = threadIdx.x;
    int g = blockIdx.x >> 7;                         // 128 blocks per graph
    int cbase = g * NPG;
    int fbase = blockIdx.x * 128;
    int wave = tid >> 6;                             // 8 waves = 8 slices
    int lane = tid & 63;

    for (int c = tid; c < 2048; c += 512) {
        int cc = cbase + c;
        float px = pos[cc * 3 + 0];
        float py = pos[cc * 3 + 1];
        float pz = pos[cc * 3 + 2];
        cp[c] = make_float4(-2.f * px, -2.f * py, -2.f * pz,
                            px * px + py * py + pz * pz);
    }

    int nA = lane, nB = lane + 64;
    float fxA = pos_skip[(fbase + nA) * 3 + 0];
    float fyA = pos_skip[(fbase + nA) * 3 + 1];
    float fzA = pos_skip[(fbase + nA) * 3 + 2];
    float fxB = pos_skip[(fbase + nB) * 3 + 0];
    float fyB = pos_skip[(fbase + nB) * 3 + 1];
    float fzB = pos_skip[(fbase + nB) * 3 + 2];
    __syncthreads();

    const float4* cps = cp + wave * 256;
    float k0A = 3.4028235e38f, k1A = 3.4028235e38f, k2A = 3.4028235e38f;
    float k0B = 3.4028235e38f, k1B = 3.4028235e38f, k2B = 3.4028235e38f;
#pragma unroll
    for (int j = 0; j < 8; ++j) {
        float mA = 3.4028235e38f, mB = 3.4028235e38f;
#pragma unroll 8
        for (int i = 0; i < 32; ++i) {
            float4 cc = cps[j * 32 + i];             // wave-uniform broadcast read
            float dA = fmaf(cc.x, fxA, cc.w);        // |f|^2 dropped: rank-equiv
            dA = fmaf(cc.y, fyA, dA);
            dA = fmaf(cc.z, fzA, dA);
            mA = fminf(mA, dA);
            float dB = fmaf(cc.x, fxB, cc.w);
            dB = fmaf(cc.y, fyB, dB);
            dB = fmaf(cc.z, fzB, dB);
            mB = fminf(mB, dB);
        }
        unsigned cid = (unsigned)(wave * 8 + j);     // global chunk id [0,64)
        float keyA = __uint_as_float((__float_as_uint(mA) & 0xFFFFFFC0u) | cid);
        float tA = fmaxf(k1A, keyA);
        k2A = fminf(k2A, tA);
        k1A = __builtin_amdgcn_fmed3f(k0A, k1A, keyA);
        k0A = fminf(k0A, keyA);
        float keyB = __uint_as_float((__float_as_uint(mB) & 0xFFFFFFC0u) | cid);
        float tB = fmaxf(k1B, keyB);
        k2B = fminf(k2B, tB);
        k1B = __builtin_amdgcn_fmed3f(k0B, k1B, keyB);
        k0B = fminf(k0B, keyB);
    }
    pk[wave][nA][0] = k0A; pk[wave][nA][1] = k1A; pk[wave][nA][2] = k2A;
    pk[wave][nB][0] = k0B; pk[wave][nB][1] = k1B; pk[wave][nB][2] = k2B;
    __syncthreads();

    // global top-3 chunks per node (24 keys; ids distinct by construction)
    if (tid < 128) {
        int n = tid;
        float m0 = 3.4028235e38f, m1 = 3.4028235e38f, m2 = 3.4028235e38f;
#pragma unroll
        for (int s = 0; s < 8; ++s)
#pragma unroll
            for (int r = 0; r < 3; ++r) {
                float k = pk[s][n][r];
                float t = fmaxf(m1, k);
                m2 = fminf(m2, t);
                m1 = __builtin_amdgcn_fmed3f(m0, m1, k);
                m0 = fminf(m0, k);
            }
        chosen[n][0] = (int)(__float_as_uint(m0) & 63u);
        chosen[n][1] = (int)(__float_as_uint(m1) & 63u);
        chosen[n][2] = (int)(__float_as_uint(m2) & 63u);
    }
    __syncthreads();

    // rescan the 3 chosen chunks exactly (threads 0..383: node = tid&127,
    // chunk slot j = tid>>7); lane-rotated gather breaks bank aliasing.
    if ((tid >> 7) < 3) {
        int n = tid & 127;
        int j = tid >> 7;
        int cid = chosen[n][j];
        int fn = fbase + n;
        float gx = pos_skip[fn * 3 + 0], gy = pos_skip[fn * 3 + 1], gz = pos_skip[fn * 3 + 2];
        float gq = gx * gx + gy * gy + gz * gz;
        unsigned long long m0 = ~0ull, m1 = ~0ull, m2 = ~0ull;
#pragma unroll 4
        for (int i = 0; i < 32; ++i) {
            int ii = (i + lane) & 31;
            float4 cc = cp[cid * 32 + ii];
            float d = gq + cc.w;
            d = fmaf(cc.x, gx, d);
            d = fmaf(cc.y, gy, d);
            d = fmaf(cc.z, gz, d);
            d = fmaxf(d, 0.f);
            unsigned c = (unsigned)(cbase + cid * 32 + ii);
            unsigned long long kk = ((unsigned long long)__float_as_uint(d) << 32) | c;
            unsigned long long t1 = m0 > kk ? m0 : kk; m0 = m0 < kk ? m0 : kk;
            unsigned long long t2 = m1 > t1 ? m1 : t1; m1 = m1 < t1 ? m1 : t1;
            m2 = m2 < t2 ? m2 : t2;
        }
        fin[j][n][0] = m0; fin[j][n][1] = m1; fin[j][n][2] = m2;
    }
    __syncthreads();

    if (tid < 128) {
        int n = tid;
        int fn = fbase + n;
        unsigned long long m0 = ~0ull, m1 = ~0ull, m2 = ~0ull;
#pragma unroll
        for (int j = 0; j < 3; ++j)
#pragma unroll
            for (int r = 0; r < 3; ++r) {
                unsigned long long kk = fin[j][n][r];
                unsigned long long t1 = m0 > kk ? m0 : kk; m0 = m0 < kk ? m0 : kk;
                unsigned long long t2 = m1 > t1 ? m1 : t1; m1 = m1 < t1 ? m1 : t1;
                m2 = m2 < t2 ? m2 : t2;
            }
        float d0 = __uint_as_float((unsigned)(m0 >> 32));
        float d1 = __uint_as_float((unsigned)(m1 >> 32));
        float d2 = __uint_as_float((unsigned)(m2 >> 32));
        float w0 = 1.f / fmaxf(d0, 1e-16f);
        float w1 = 1.f / fmaxf(d1, 1e-16f);
        float w2 = 1.f / fmaxf(d2, 1e-16f);
        float inv = 1.f / (w0 + w1 + w2);
        wFin[n][0] = w0 * inv; wFin[n][1] = w1 * inv; wFin[n][2] = w2 * inv;
        iFin[n][0] = (int)(m0 & 0xffffffffull);
        iFin[n][1] = (int)(m1 & 0xffffffffull);
        iFin[n][2] = (int)(m2 & 0xffffffffull);
        float gx = pos_skip[fn * 3 + 0], gy = pos_skip[fn * 3 + 1], gz = pos_skip[fn * 3 + 2];
        out_pos[fn * 3 + 0] = gx; out_pos[fn * 3 + 1] = gy; out_pos[fn * 3 + 2] = gz;
        out_batch[fn] = (float)batch_skip[fn];
    }
    __syncthreads();

    int n2 = tid >> 2, part = tid & 3;               // 512 thr -> 128 nodes x 4
    int f2 = fbase + n2;
    float4* h04 = (float4*)(h0 + (size_t)f2 * 32);
    if (part < 2) {
        const float4* x4 = (const float4*)x;
        float w0 = wFin[n2][0], w1 = wFin[n2][1], w2 = wFin[n2][2];
        int a0 = iFin[n2][0] * 4, a1 = iFin[n2][1] * 4, a2 = iFin[n2][2] * 4;
#pragma unroll
        for (int j = 0; j < 2; ++j) {
            int cj = part * 2 + j;
            float4 v0 = x4[a0 + cj], v1 = x4[a1 + cj], v2 = x4[a2 + cj];
            float4 r;
            r.x = w0 * v0.x + w1 * v1.x + w2 * v2.x;
            r.y = w0 * v0.y + w1 * v1.y + w2 * v2.y;
            r.z = w0 * v0.z + w1 * v1.z + w2 * v2.z;
            r.w = w0 * v0.w + w1 * v1.w + w2 * v2.w;
            h04[cj] = r;
        }
    } else {
        const float4* xs4 = (const float4*)x_skip;
#pragma unroll
        for (int j = 0; j < 2; ++j) {
            int cj = (part - 2) * 2 + j;
            h04[4 + cj] = xs4[f2 * 4 + cj];
        }
    }
}

// ---------------------------------------------------------------------------
// token prep 1: Kt/Vt = gt @ W^T + b + pe   -> KtVt [B][2][16][64]
// ---------------------------------------------------------------------------
__global__ __launch_bounds__(128)
void k_tokens1(const float* __restrict__ gt,
               const float* __restrict__ Wk_w, const float* __restrict__ Wk_b,
               const float* __restrict__ Wv_w, const float* __restrict__ Wv_b,
               float* __restrict__ KtVt)
{
    int b = blockIdx.x >> 4;
    int t = blockIdx.x & 15;
    int which = threadIdx.x >> 6;
    int d = threadIdx.x & 63;
    const float* W = which ? Wv_w : Wk_w;
    const float* bias = which ? Wv_b : Wk_b;
    const float4* row = (const float4*)(gt + (size_t)(b * 16 + t) * 1024);
    const float4* wr = (const float4*)(W + (size_t)d * 1024);
    float acc = 0.f;
    for (int c = 0; c < 256; ++c) {
        float4 a = row[c], w = wr[c];
        acc += a.x * w.x; acc += a.y * w.y; acc += a.z * w.z; acc += a.w * w.w;
    }
    int i2 = d >> 1;
    float dv = expf((float)(2 * i2) * (-0.14391156831212787f)); // -ln(10000)/64
    float ang = (float)t * dv;
    float pe = (d & 1) ? cosf(ang) : sinf(ang);
    KtVt[((size_t)(b * 2 + which) * 16 + t) * 64 + d] = acc + bias[d] + pe;
}

// ---------------------------------------------------------------------------
// token prep 2 (per graph): k/v head proj; V2 = out_w-folded v heads into LDS;
// emits Mfold[g][th=t*4+h][4] and v2f[g] (V2^T, bf16 A-frag layout).
// ---------------------------------------------------------------------------
__global__ __launch_bounds__(256)
void k_tokens2(const float* __restrict__ KtVt,
               const float* __restrict__ in_proj_w, const float* __restrict__ in_proj_b,
               const float* __restrict__ out_w,
               const float* __restrict__ Wq_w, const float* __restrict__ Wq_b,
               float* __restrict__ Mfold, uint4* __restrict__ v2fG)
{
    int b = blockIdx.x;
    int tid = threadIdx.x;
    __shared__ float KtL[1024], VtL[1024], vv[1024], kproj[1024];
    __shared__ float v2L[4096];
    __shared__ float qWs[192], qbs[64];
    for (int idx = tid; idx < 1024; idx += 256) {
        KtL[idx] = KtVt[(size_t)(b * 2 + 0) * 1024 + idx];
        VtL[idx] = KtVt[(size_t)(b * 2 + 1) * 1024 + idx];
    }
    __syncthreads();
    for (int idx = tid; idx < 2048; idx += 256) {
        int which = idx >> 10; int td = idx & 1023; int t = td >> 6; int j = td & 63;
        int r = (which ? 128 : 64) + j;
        const float* w = in_proj_w + (size_t)r * 64;
        const float* src = which ? VtL : KtL;
        float acc = in_proj_b[r];
#pragma unroll 8
        for (int dd = 0; dd < 64; ++dd) acc += src[t * 64 + dd] * w[dd];
        if (which) vv[t * 64 + j] = acc;
        else kproj[t * 64 + j] = acc;
    }
    for (int idx = tid; idx < 192; idx += 256) {
        int c = idx >> 6; int j = idx & 63;
        float acc = 0.f;
        for (int dd = 0; dd < 64; ++dd) acc += in_proj_w[(size_t)j * 64 + dd] * Wq_w[dd * 3 + c];
        qWs[c * 64 + j] = acc;
    }
    for (int j = tid; j < 64; j += 256) {
        float acc = in_proj_b[j];
        for (int dd = 0; dd < 64; ++dd) acc += in_proj_w[(size_t)j * 64 + dd] * Wq_b[dd];
        qbs[j] = acc;
    }
    __syncthreads();
    for (int idx = tid; idx < 4096; idx += 256) {
        int jo = idx & 63; int th2 = idx >> 6; int h = th2 & 3; int t = th2 >> 2;
        float acc = 0.f;
#pragma unroll
        for (int dd = 0; dd < 16; ++dd)
            acc += vv[t * 64 + h * 16 + dd] * out_w[(size_t)jo * 64 + h * 16 + dd];
        v2L[(t * 4 + h) * 64 + jo] = acc;
    }
    {
        int th = tid >> 2, c = tid & 3;
        int t = th >> 2, h = th & 3;
        float acc = 0.f;
#pragma unroll
        for (int dd = h * 16; dd < h * 16 + 16; ++dd) {
            float w = (c == 0) ? qWs[dd] : (c == 1) ? qWs[64 + dd]
                    : (c == 2) ? qWs[128 + dd] : qbs[dd];
            acc += w * kproj[t * 64 + dd];
        }
        Mfold[((size_t)b * 64 + th) * 4 + c] = 0.25f * acc;
    }
    __syncthreads();
    for (int it = tid; it < 512; it += 256) {
        int lane = it & 63, fi = it >> 6;
        int mi = fi >> 1, step = fi & 1;
        int outd = mi * 16 + (lane & 15);
        int th0 = step * 32 + (lane >> 4) * 8;
        uint4 v;
        v.x = f2b_pack(v2L[(th0 + 0) * 64 + outd], v2L[(th0 + 1) * 64 + outd]);
        v.y = f2b_pack(v2L[(th0 + 2) * 64 + outd], v2L[(th0 + 3) * 64 + outd]);
        v.z = f2b_pack(v2L[(th0 + 4) * 64 + outd], v2L[(th0 + 5) * 64 + outd]);
        v.w = f2b_pack(v2L[(th0 + 6) * 64 + outd], v2L[(th0 + 7) * 64 + outd]);
        v2fG[((size_t)b * 8 + fi) * 64 + lane] = v;
    }
}

// ---------------------------------------------------------------------------
// per-edge cross attention, MFMA PV. expf -> __expf (softmax renormalizes;
// v_exp_f32 path, 64 calls/thread was a libm chain).
// ---------------------------------------------------------------------------
__global__ __launch_bounds__(256)
void k_edge_attn(const float* __restrict__ ps, const int* __restrict__ ei,
                 const float* __restrict__ Mfold, const uint4* __restrict__ v2f,
                 const float* __restrict__ ob,
                 unsigned short* __restrict__ Pf, float* __restrict__ cnt)
{
    __shared__ unsigned attL[4 * 64 * 34];     // 34.8 KB; per-wave 64x34-dword slab
    int tid = threadIdx.x;
    int wave = tid >> 6, lane = tid & 63, q = lane >> 4, c15 = lane & 15;
    int g = blockIdx.x >> 7;                   // 128 blocks per graph
    int e = blockIdx.x * 256 + tid;
    int s = ei[e], d = ei[EE + e];
    atomicAdd(&cnt[d], 1.f);
    float sx = ps[s * 3], sy = ps[s * 3 + 1], sz = ps[s * 3 + 2];
    float dx = ps[d * 3], dy = ps[d * 3 + 1], dz = ps[d * 3 + 2];
    float px = dx - sx, py = dy - sy, pz = dz - sz;
    float ex = 0.5f * (dx + sx), ey = 0.5f * (dy + sy), ez = 0.5f * (dz + sz);

    const float4* Mg = (const float4*)Mfold + (size_t)g * 64;
    float sc[64];
#pragma unroll
    for (int th = 0; th < 64; ++th) {
        float4 m = Mg[th];
        sc[th] = ex * m.x + ey * m.y + ez * m.z + m.w;
    }
#pragma unroll
    for (int h = 0; h < 4; ++h) {
        float mx = sc[h];
#pragma unroll
        for (int t = 1; t < 16; ++t) mx = fmaxf(mx, sc[t * 4 + h]);
        float ssum = 0.f;
#pragma unroll
        for (int t = 0; t < 16; ++t) {
            float eo = __expf(sc[t * 4 + h] - mx);
            sc[t * 4 + h] = eo; ssum += eo;
        }
        float inv = 1.f / ssum;
#pragma unroll
        for (int t = 0; t < 16; ++t) sc[t * 4 + h] *= inv;
    }
    unsigned* slab = attL + wave * 64 * 34;
#pragma unroll
    for (int k = 0; k < 16; ++k) {
        uint2 v;
        v.x = f2b_pack(sc[4 * k + 0], sc[4 * k + 1]);
        v.y = f2b_pack(sc[4 * k + 2], sc[4 * k + 3]);
        *(uint2*)&slab[lane * 34 + 2 * k] = v;
    }
    __syncthreads();

    uint4 v2a[4][2];
#pragma unroll
    for (int mi = 0; mi < 4; ++mi)
#pragma unroll
        for (int st = 0; st < 2; ++st)
            v2a[mi][st] = v2f[((size_t)g * 8 + mi * 2 + st) * 64 + lane];

    f32x4 acc[4][4];
#pragma unroll
    for (int mi = 0; mi < 4; ++mi)
#pragma unroll
        for (int nt = 0; nt < 4; ++nt) acc[mi][nt] = (f32x4){0.f, 0.f, 0.f, 0.f};

#pragma unroll
    for (int nt = 0; nt < 4; ++nt) {
        const unsigned* rb = &slab[(nt * 16 + c15) * 34];
        uint4 b0 = *(const uint4*)&rb[q * 4];
        uint4 b1 = *(const uint4*)&rb[16 + q * 4];
#pragma unroll
        for (int mi = 0; mi < 4; ++mi) {
            acc[mi][nt] = __builtin_amdgcn_mfma_f32_16x16x32_bf16(bc8(v2a[mi][0]), bc8(b0), acc[mi][nt], 0, 0, 0);
            acc[mi][nt] = __builtin_amdgcn_mfma_f32_16x16x32_bf16(bc8(v2a[mi][1]), bc8(b1), acc[mi][nt], 0, 0, 0);
        }
    }
    __syncthreads();

    float4 obv[4];
#pragma unroll
    for (int mi = 0; mi < 4; ++mi) obv[mi] = *(const float4*)(ob + mi * 16 + q * 4);
#pragma unroll
    for (int mi = 0; mi < 4; ++mi)
#pragma unroll
        for (int nt = 0; nt < 4; ++nt) {
            f32x4 a = acc[mi][nt];
            uint2 v;
            v.x = f2b_pack(a[0] + obv[mi].x, a[1] + obv[mi].y);
            v.y = f2b_pack(a[2] + obv[mi].z, a[3] + obv[mi].w);
            *(uint2*)&slab[(nt * 16 + c15) * 34 + mi * 8 + q * 2] = v;
        }
    __syncthreads();

    uint4* Pf4 = (uint4*)Pf;
#pragma unroll
    for (int et = 0; et < 4; ++et) {
        int etg = blockIdx.x * 16 + wave * 4 + et;
#pragma unroll
        for (int st = 0; st < 2; ++st) {
            uint4 w = *(const uint4*)&slab[(et * 16 + c15) * 34 + st * 16 + q * 4];
            Pf4[((size_t)etg * 3 + st) * 64 + lane] = w;
        }
    }
    int et2 = e >> 4, eL = e & 15;
    size_t tb = ((size_t)(et2 * 3 + 2) * 64 + 0 * 16 + eL) * 8;
    uint2 t0; t0.x = f2b_pack(px, py); t0.y = f2b_pack(pz, 1.0f);
    *(uint2*)(Pf + tb) = t0;
    uint2 z2; z2.x = 0u; z2.y = 0u;
    *(uint2*)(Pf + tb + 4) = z2;
#pragma unroll
    for (int quad = 1; quad < 4; ++quad) {
        size_t zb = ((size_t)(et2 * 3 + 2) * 64 + quad * 16 + eL) * 8;
        uint4 z4; z4.x = 0u; z4.y = 0u; z4.z = 0u; z4.w = 0u;
        *(uint4*)(Pf + zb) = z4;
    }
}

// ---------------------------------------------------------------------------
// fused repack of all 3 layers' nn_w/nn_b -> bf16 B-fragment streams
// ---------------------------------------------------------------------------
static __device__ inline void repack_one(const float* __restrict__ nw,
                                         const float* __restrict__ nb,
                                         unsigned short* __restrict__ Wf, int idx)
{
    int jj = idx & 7;
    int lane = (idx >> 3) & 63;
    int rest = idx >> 9;
    int s = rest % 3;
    int jt = rest / 3;
    int j = jt * 16 + (lane & 15);
    int k = s * 32 + (lane >> 4) * 8 + jj;
    float v;
    if (k < 64)       v = nw[(size_t)j * 67 + 3 + k];
    else if (k < 67)  v = nw[(size_t)j * 67 + (k - 64)];
    else if (k == 67) v = nb[j];
    else              v = 0.f;
    Wf[idx] = f2b(v);
}

__global__ __launch_bounds__(256)
void k_repackAll(const float* __restrict__ nw0, const float* __restrict__ nb0,
                 const float* __restrict__ nw1, const float* __restrict__ nb1,
                 const float* __restrict__ nw2, const float* __restrict__ nb2,
                 unsigned short* __restrict__ Wf0, unsigned short* __restrict__ Wf1,
                 unsigned short* __restrict__ Wf2)
{
    int idx = blockIdx.x * 256 + threadIdx.x;
    if (idx < 98304)        repack_one(nw0, nb0, Wf0, idx);
    else if (idx < 196608)  repack_one(nw1, nb1, Wf1, idx - 98304);
    else                    repack_one(nw2, nb2, Wf2, idx - 196608);
}

// ---------------------------------------------------------------------------
// MFMA edge pass, split-K wave pairs — EXACT R4 geometry (128 edges/block,
// grid 1024, 4 blocks/CU; measured 47.2us, WRITE 16.4MB). Five geometry
// perturbations (R6-R9) all regressed 8-364us: this config is the L2-
// residency sweet spot for the Wf stream. Only change: #pragma unroll 2 on
// the i2 loop (two independent Wf->MFMA chains for latency hiding).
// ---------------------------------------------------------------------------
template<int CO>
__global__ __launch_bounds__(256, 4)
void k_conv_mfma(const uint4* __restrict__ Pf, const float* __restrict__ hin,
                 const int* __restrict__ ei, const uint4* __restrict__ Wf,
                 float* __restrict__ aggr)
{
    __shared__ float hL[128 * 36];             // 18.4 KB
    __shared__ int sL[128];
    __shared__ int dL[128];
    constexpr int REDSZ = (CO == 16) ? 2 * 64 * 17 : 4;
    __shared__ float red[REDSZ];               // 8.7 KB (CO=16 only)

    int tid = threadIdx.x;
    int e0 = blockIdx.x * 128;
    if (tid < 128) sL[tid] = ei[e0 + tid];
    else           dL[tid - 128] = ei[EE + e0 + (tid - 128)];
    __syncthreads();
    for (int idx = tid; idx < 1024; idx += 256) {
        int row = idx >> 3, c = idx & 7;
        const float4* hr = (const float4*)(hin + (size_t)sL[row] * 32);
        *(float4*)&hL[row * 36 + c * 4] = hr[c];
    }
    __syncthreads();

    int wave = tid >> 6, lane = tid & 63, quad = lane >> 4, col = lane & 15;
    int group = wave >> 1, half = wave & 1;

    uint4 a[4][3];
    int et0 = blockIdx.x * 8 + group * 4;
#pragma unroll
    for (int st = 0; st < 4; ++st)
#pragma unroll
        for (int s = 0; s < 3; ++s)
            a[st][s] = Pf[((size_t)(et0 + st) * 3 + s) * 64 + lane];

    float msg[4][4];
#pragma unroll
    for (int st = 0; st < 4; ++st)
#pragma unroll
        for (int r = 0; r < 4; ++r) msg[st][r] = 0.f;

    int ibase = (CO == 32) ? 0 : half * 16;
    constexpr int NI2 = (CO == 32) ? 16 : 8;   // i-pairs per wave

#pragma unroll 2
    for (int i2 = 0; i2 < NI2; ++i2) {
        float2 hv2[4][4];
#pragma unroll
        for (int st = 0; st < 4; ++st)
#pragma unroll
            for (int r = 0; r < 4; ++r)
                hv2[st][r] = *(const float2*)&hL[(group * 64 + st * 16 + quad * 4 + r) * 36
                                                 + ibase + i2 * 2];
#pragma unroll
        for (int ii = 0; ii < 2; ++ii) {
            int i = ibase + i2 * 2 + ii;
            int jt = (CO == 32) ? (i * 2 + half) : i;
            uint4 b0 = Wf[((size_t)jt * 3 + 0) * 64 + lane];
            uint4 b1 = Wf[((size_t)jt * 3 + 1) * 64 + lane];
            uint4 b2 = Wf[((size_t)jt * 3 + 2) * 64 + lane];
#pragma unroll
            for (int st = 0; st < 4; ++st) {
                f32x4 c = {0.f, 0.f, 0.f, 0.f};
                c = __builtin_amdgcn_mfma_f32_16x16x32_bf16(bc8(a[st][0]), bc8(b0), c, 0, 0, 0);
                c = __builtin_amdgcn_mfma_f32_16x16x32_bf16(bc8(a[st][1]), bc8(b1), c, 0, 0, 0);
                c = __builtin_amdgcn_mfma_f32_16x16x32_bf16(bc8(a[st][2]), bc8(b2), c, 0, 0, 0);
#pragma unroll
                for (int r = 0; r < 4; ++r) {
                    float hv = ii ? hv2[st][r].y : hv2[st][r].x;
                    msg[st][r] += hv * fmaxf(c[r], 0.f);
                }
            }
        }
    }

    if (CO == 32) {
#pragma unroll
        for (int st = 0; st < 4; ++st)
#pragma unroll
            for (int r = 0; r < 4; ++r) {
                int dv = dL[group * 64 + st * 16 + quad * 4 + r];
                atomicAdd(&aggr[(size_t)dv * 32 + half * 16 + col], msg[st][r]);
            }
    } else {
        if (half == 1) {
#pragma unroll
            for (int st = 0; st < 4; ++st)
#pragma unroll
                for (int r = 0; r < 4; ++r)
                    red[group * 64 * 17 + lane * 17 + st * 4 + r] = msg[st][r];
        }
        __syncthreads();
        if (half == 0) {
#pragma unroll
            for (int st = 0; st < 4; ++st)
#pragma unroll
                for (int r = 0; r < 4; ++r) {
                    float m = msg[st][r] + red[group * 64 * 17 + lane * 17 + st * 4 + r];
                    int dv = dL[group * 64 + st * 16 + quad * 4 + r];
                    atomicAdd(&aggr[(size_t)dv * 16 + col], m);
                }
        }
    }
}

// ---------------------------------------------------------------------------
// node update: h' = relu(aggr/cnt + h @ root + bias); zeroes aggr for the
// next layer's atomic pass. hr reads vectorized to float4 (was 32 scalar).
// ---------------------------------------------------------------------------
template<int CO>
__global__ __launch_bounds__(256)
void k_update(float* __restrict__ aggr, const float* __restrict__ cnt,
              const float* __restrict__ hin, const float* __restrict__ root,
              const float* __restrict__ bias, float* __restrict__ hout)
{
    __shared__ float rL[32 * CO];
    __shared__ float bL[CO];
    int tid = threadIdx.x;
    for (int idx = tid; idx < 32 * CO; idx += 256) rL[idx] = root[idx];
    if (tid < CO) bL[tid] = bias[tid];
    __syncthreads();
    int gid = blockIdx.x * 256 + tid;
    int v = gid / CO;
    int o = gid % CO;
    float acc = aggr[gid] / fmaxf(cnt[v], 1.f) + bL[o];
    aggr[gid] = 0.f;                    // prep next layer's scatter
    const float4* hr4 = (const float4*)(hin + (size_t)v * 32);
#pragma unroll
    for (int i4 = 0; i4 < 8; ++i4) {
        float4 hv = hr4[i4];
        acc += hv.x * rL[(i4 * 4 + 0) * CO + o];
        acc += hv.y * rL[(i4 * 4 + 1) * CO + o];
        acc += hv.z * rL[(i4 * 4 + 2) * CO + o];
        acc += hv.w * rL[(i4 * 4 + 3) * CO + o];
    }
    hout[gid] = fmaxf(acc, 0.f);
}

// ---------------------------------------------------------------------------
extern "C" void kernel_launch(void* const* d_in, const int* in_sizes, int n_in,
                              void* d_out, int out_size, void* d_ws, size_t ws_size,
                              hipStream_t stream)
{
    const float* x          = (const float*)d_in[0];
    const float* pos        = (const float*)d_in[1];
    const float* x_skip     = (const float*)d_in[3];
    const float* pos_skip   = (const float*)d_in[4];
    const int*   batch_skip = (const int*)  d_in[5];
    const int*   ei         = (const int*)  d_in[6];
    const float* gt         = (const float*)d_in[7];
    const float* Wq_w       = (const float*)d_in[8];
    const float* Wq_b       = (const float*)d_in[9];
    const float* Wk_w       = (const float*)d_in[10];
    const float* Wk_b       = (const float*)d_in[11];
    const float* Wv_w       = (const float*)d_in[12];
    const float* Wv_b       = (const float*)d_in[13];
    const float* in_proj_w  = (const float*)d_in[14];
    const float* in_proj_b  = (const float*)d_in[15];
    const float* out_w      = (const float*)d_in[16];
    const float* out_b      = (const float*)d_in[17];
    const float* nn_w0 = (const float*)d_in[18]; const float* nn_b0 = (const float*)d_in[19];
    const float* root0 = (const float*)d_in[20]; const float* bias0 = (const float*)d_in[21];
    const float* nn_w1 = (const float*)d_in[22]; const float* nn_b1 = (const float*)d_in[23];
    const float* root1 = (const float*)d_in[24]; const float* bias1 = (const float*)d_in[25];
    const float* nn_w2 = (const float*)d_in[26]; const float* nn_b2 = (const float*)d_in[27];
    const float* root2 = (const float*)d_in[28]; const float* bias2 = (const float*)d_in[29];

    char* wsb = (char*)d_ws;
    size_t off = 0;
    auto carve = [&](size_t bytes) { char* p = wsb + off; off += (bytes + 255) & ~(size_t)255; return p; };
    float* aggr = (float*)carve((size_t)MM * 32 * 4);   // aggr then cnt: one memset
    float* cnt  = (float*)carve((size_t)MM * 4);
    float* hA   = (float*)carve((size_t)MM * 32 * 4);
    float* hB   = (float*)carve((size_t)MM * 32 * 4);
    unsigned short* Pf  = (unsigned short*)carve((size_t)EE * 96 * 2);
    unsigned short* Wf0 = (unsigned short*)carve((size_t)1024 * 96 * 2);
    unsigned short* Wf1 = (unsigned short*)carve((size_t)1024 * 96 * 2);
    unsigned short* Wf2 = (unsigned short*)carve((size_t)512 * 96 * 2);
    float* Mfold = (float*)carve((size_t)NB * 64 * 4 * 4);
    uint4* v2f   = (uint4*)carve((size_t)NB * 8 * 64 * 16);
    float* KtVt  = (float*)carve((size_t)NB * 2 * 16 * 64 * 4);

    float* h_final   = (float*)d_out;                 // [M,16]
    float* out_pos   = (float*)d_out + (size_t)MM * 16;
    float* out_batch = (float*)d_out + (size_t)MM * 19;

    // one memset covers aggr (MM*32) + cnt (MM) — adjacent carves
    hipMemsetAsync(aggr, 0, ((size_t)MM * 32 + MM) * sizeof(float), stream);

    k_knn<<<MM / 128, 512, 0, stream>>>(pos, pos_skip, x, x_skip, batch_skip,
                                        hA, out_pos, out_batch);
    k_tokens1<<<64, 128, 0, stream>>>(gt, Wk_w, Wk_b, Wv_w, Wv_b, KtVt);
    k_tokens2<<<NB, 256, 0, stream>>>(KtVt, in_proj_w, in_proj_b, out_w, Wq_w, Wq_b,
                                      Mfold, v2f);
    k_edge_attn<<<EE / 256, 256, 0, stream>>>(pos_skip, ei, Mfold, v2f, out_b,
                                              Pf, cnt);
    k_repackAll<<<960, 256, 0, stream>>>(nn_w0, nn_b0, nn_w1, nn_b1, nn_w2, nn_b2,
                                         Wf0, Wf1, Wf2);

    // layer 0: hA -> hB   (update zeroes aggr for layer 1)
    k_conv_mfma<32><<<EE / 128, 256, 0, stream>>>((const uint4*)Pf, hA, ei, (const uint4*)Wf0, aggr);
    k_update<32><<<(MM * 32) / 256, 256, 0, stream>>>(aggr, cnt, hA, root0, bias0, hB);
    // layer 1: hB -> hA   (update zeroes aggr for layer 2)
    k_conv_mfma<32><<<EE / 128, 256, 0, stream>>>((const uint4*)Pf, hB, ei, (const uint4*)Wf1, aggr);
    k_update<32><<<(MM * 32) / 256, 256, 0, stream>>>(aggr, cnt, hB, root1, bias1, hA);
    // layer 2: hA -> d_out
    k_conv_mfma<16><<<EE / 128, 256, 0, stream>>>((const uint4*)Pf, hA, ei, (const uint4*)Wf2, aggr);
    k_update<16><<<(MM * 16) / 256, 256, 0, stream>>>(aggr, cnt, hA, root2, bias2, h_final);
}

// Round 11
// 345.377 us; speedup vs baseline: 2.0543x; 1.3220x over previous
//
#include <hip/hip_runtime.h>
#include <math.h>

#define NB    4        // graphs
#define NN    8192     // coarse nodes
#define MM    65536    // fine nodes
#define EE    131072   // edges
#define NPG   2048     // coarse per graph

typedef short short8 __attribute__((ext_vector_type(8)));
typedef float f32x4  __attribute__((ext_vector_type(4)));

static __device__ inline unsigned short f2b(float f) {
    unsigned u = __float_as_uint(f);
    u += 0x7fffu + ((u >> 16) & 1u);           // RNE
    return (unsigned short)(u >> 16);
}
static __device__ inline unsigned f2b_pack(float a, float b) {
    unsigned x = __float_as_uint(a); x += 0x7fffu + ((x >> 16) & 1u);
    unsigned y = __float_as_uint(b); y += 0x7fffu + ((y >> 16) & 1u);
    return (x >> 16) | (y & 0xffff0000u);
}
static __device__ inline short8 bc8(uint4 v) {
    union { uint4 u; short8 s; } c; c.u = v; return c.s;
}

// ---------------------------------------------------------------------------
// knn_interpolate (k=3), chunk-min two-phase scan (round-4 structure,
// verified -24us). Candidate transform computed inline during staging.
// 512 blocks x 512 thr; 128 fine nodes/block, 2 nodes/thread.
// ---------------------------------------------------------------------------
__global__ __launch_bounds__(512)
void k_knn(const float* __restrict__ pos, const float* __restrict__ pos_skip,
           const float* __restrict__ x, const float* __restrict__ x_skip,
           const int* __restrict__ batch_skip,
           float* __restrict__ h0, float* __restrict__ out_pos,
           float* __restrict__ out_batch)
{
    __shared__ float4 cp[2048];                      // 32 KB (-2x,-2y,-2z,|c|^2)
    __shared__ float  pk[8][128][3];                 // 12 KB per-slice top-3 chunk keys
    __shared__ int    chosen[128][3];                // 1.5 KB global top-3 chunk ids
    __shared__ unsigned long long fin[3][128][3];    // 9 KB per-chunk exact top-3
    __shared__ float  wFin[128][3];
    __shared__ int    iFin[128][3];

    int tid = threadIdx.x;
    int g = blockIdx.x >> 7;                         // 128 blocks per graph
    int cbase = g * NPG;
    int fbase = blockIdx.x * 128;
    int wave = tid >> 6;                             // 8 waves = 8 slices
    int lane = tid & 63;

    for (int c = tid; c < 2048; c += 512) {
        int cc = cbase + c;
        float px = pos[cc * 3 + 0];
        float py = pos[cc * 3 + 1];
        float pz = pos[cc * 3 + 2];
        cp[c] = make_float4(-2.f * px, -2.f * py, -2.f * pz,
                            px * px + py * py + pz * pz);
    }

    int nA = lane, nB = lane + 64;
    float fxA = pos_skip[(fbase + nA) * 3 + 0];
    float fyA = pos_skip[(fbase + nA) * 3 + 1];
    float fzA = pos_skip[(fbase + nA) * 3 + 2];
    float fxB = pos_skip[(fbase + nB) * 3 + 0];
    float fyB = pos_skip[(fbase + nB) * 3 + 1];
    float fzB = pos_skip[(fbase + nB) * 3 + 2];
    __syncthreads();

    const float4* cps = cp + wave * 256;
    float k0A = 3.4028235e38f, k1A = 3.4028235e38f, k2A = 3.4028235e38f;
    float k0B = 3.4028235e38f, k1B = 3.4028235e38f, k2B = 3.4028235e38f;
#pragma unroll
    for (int j = 0; j < 8; ++j) {
        float mA = 3.4028235e38f, mB = 3.4028235e38f;
#pragma unroll 8
        for (int i = 0; i < 32; ++i) {
            float4 cc = cps[j * 32 + i];             // wave-uniform broadcast read
            float dA = fmaf(cc.x, fxA, cc.w);        // |f|^2 dropped: rank-equiv
            dA = fmaf(cc.y, fyA, dA);
            dA = fmaf(cc.z, fzA, dA);
            mA = fminf(mA, dA);
            float dB = fmaf(cc.x, fxB, cc.w);
            dB = fmaf(cc.y, fyB, dB);
            dB = fmaf(cc.z, fzB, dB);
            mB = fminf(mB, dB);
        }
        unsigned cid = (unsigned)(wave * 8 + j);     // global chunk id [0,64)
        float keyA = __uint_as_float((__float_as_uint(mA) & 0xFFFFFFC0u) | cid);
        float tA = fmaxf(k1A, keyA);
        k2A = fminf(k2A, tA);
        k1A = __builtin_amdgcn_fmed3f(k0A, k1A, keyA);
        k0A = fminf(k0A, keyA);
        float keyB = __uint_as_float((__float_as_uint(mB) & 0xFFFFFFC0u) | cid);
        float tB = fmaxf(k1B, keyB);
        k2B = fminf(k2B, tB);
        k1B = __builtin_amdgcn_fmed3f(k0B, k1B, keyB);
        k0B = fminf(k0B, keyB);
    }
    pk[wave][nA][0] = k0A; pk[wave][nA][1] = k1A; pk[wave][nA][2] = k2A;
    pk[wave][nB][0] = k0B; pk[wave][nB][1] = k1B; pk[wave][nB][2] = k2B;
    __syncthreads();

    // global top-3 chunks per node (24 keys; ids distinct by construction)
    if (tid < 128) {
        int n = tid;
        float m0 = 3.4028235e38f, m1 = 3.4028235e38f, m2 = 3.4028235e38f;
#pragma unroll
        for (int s = 0; s < 8; ++s)
#pragma unroll
            for (int r = 0; r < 3; ++r) {
                float k = pk[s][n][r];
                float t = fmaxf(m1, k);
                m2 = fminf(m2, t);
                m1 = __builtin_amdgcn_fmed3f(m0, m1, k);
                m0 = fminf(m0, k);
            }
        chosen[n][0] = (int)(__float_as_uint(m0) & 63u);
        chosen[n][1] = (int)(__float_as_uint(m1) & 63u);
        chosen[n][2] = (int)(__float_as_uint(m2) & 63u);
    }
    __syncthreads();

    // rescan the 3 chosen chunks exactly (threads 0..383: node = tid&127,
    // chunk slot j = tid>>7); lane-rotated gather breaks bank aliasing.
    if ((tid >> 7) < 3) {
        int n = tid & 127;
        int j = tid >> 7;
        int cid = chosen[n][j];
        int fn = fbase + n;
        float gx = pos_skip[fn * 3 + 0], gy = pos_skip[fn * 3 + 1], gz = pos_skip[fn * 3 + 2];
        float gq = gx * gx + gy * gy + gz * gz;
        unsigned long long m0 = ~0ull, m1 = ~0ull, m2 = ~0ull;
#pragma unroll 4
        for (int i = 0; i < 32; ++i) {
            int ii = (i + lane) & 31;
            float4 cc = cp[cid * 32 + ii];
            float d = gq + cc.w;
            d = fmaf(cc.x, gx, d);
            d = fmaf(cc.y, gy, d);
            d = fmaf(cc.z, gz, d);
            d = fmaxf(d, 0.f);
            unsigned c = (unsigned)(cbase + cid * 32 + ii);
            unsigned long long kk = ((unsigned long long)__float_as_uint(d) << 32) | c;
            unsigned long long t1 = m0 > kk ? m0 : kk; m0 = m0 < kk ? m0 : kk;
            unsigned long long t2 = m1 > t1 ? m1 : t1; m1 = m1 < t1 ? m1 : t1;
            m2 = m2 < t2 ? m2 : t2;
        }
        fin[j][n][0] = m0; fin[j][n][1] = m1; fin[j][n][2] = m2;
    }
    __syncthreads();

    if (tid < 128) {
        int n = tid;
        int fn = fbase + n;
        unsigned long long m0 = ~0ull, m1 = ~0ull, m2 = ~0ull;
#pragma unroll
        for (int j = 0; j < 3; ++j)
#pragma unroll
            for (int r = 0; r < 3; ++r) {
                unsigned long long kk = fin[j][n][r];
                unsigned long long t1 = m0 > kk ? m0 : kk; m0 = m0 < kk ? m0 : kk;
                unsigned long long t2 = m1 > t1 ? m1 : t1; m1 = m1 < t1 ? m1 : t1;
                m2 = m2 < t2 ? m2 : t2;
            }
        float d0 = __uint_as_float((unsigned)(m0 >> 32));
        float d1 = __uint_as_float((unsigned)(m1 >> 32));
        float d2 = __uint_as_float((unsigned)(m2 >> 32));
        float w0 = 1.f / fmaxf(d0, 1e-16f);
        float w1 = 1.f / fmaxf(d1, 1e-16f);
        float w2 = 1.f / fmaxf(d2, 1e-16f);
        float inv = 1.f / (w0 + w1 + w2);
        wFin[n][0] = w0 * inv; wFin[n][1] = w1 * inv; wFin[n][2] = w2 * inv;
        iFin[n][0] = (int)(m0 & 0xffffffffull);
        iFin[n][1] = (int)(m1 & 0xffffffffull);
        iFin[n][2] = (int)(m2 & 0xffffffffull);
        float gx = pos_skip[fn * 3 + 0], gy = pos_skip[fn * 3 + 1], gz = pos_skip[fn * 3 + 2];
        out_pos[fn * 3 + 0] = gx; out_pos[fn * 3 + 1] = gy; out_pos[fn * 3 + 2] = gz;
        out_batch[fn] = (float)batch_skip[fn];
    }
    __syncthreads();

    int n2 = tid >> 2, part = tid & 3;               // 512 thr -> 128 nodes x 4
    int f2 = fbase + n2;
    float4* h04 = (float4*)(h0 + (size_t)f2 * 32);
    if (part < 2) {
        const float4* x4 = (const float4*)x;
        float w0 = wFin[n2][0], w1 = wFin[n2][1], w2 = wFin[n2][2];
        int a0 = iFin[n2][0] * 4, a1 = iFin[n2][1] * 4, a2 = iFin[n2][2] * 4;
#pragma unroll
        for (int j = 0; j < 2; ++j) {
            int cj = part * 2 + j;
            float4 v0 = x4[a0 + cj], v1 = x4[a1 + cj], v2 = x4[a2 + cj];
            float4 r;
            r.x = w0 * v0.x + w1 * v1.x + w2 * v2.x;
            r.y = w0 * v0.y + w1 * v1.y + w2 * v2.y;
            r.z = w0 * v0.z + w1 * v1.z + w2 * v2.z;
            r.w = w0 * v0.w + w1 * v1.w + w2 * v2.w;
            h04[cj] = r;
        }
    } else {
        const float4* xs4 = (const float4*)x_skip;
#pragma unroll
        for (int j = 0; j < 2; ++j) {
            int cj = (part - 2) * 2 + j;
            h04[4 + cj] = xs4[f2 * 4 + cj];
        }
    }
}

// ---------------------------------------------------------------------------
// token prep 1: Kt/Vt = gt @ W^T + b + pe   -> KtVt [B][2][16][64]
// ---------------------------------------------------------------------------
__global__ __launch_bounds__(128)
void k_tokens1(const float* __restrict__ gt,
               const float* __restrict__ Wk_w, const float* __restrict__ Wk_b,
               const float* __restrict__ Wv_w, const float* __restrict__ Wv_b,
               float* __restrict__ KtVt)
{
    int b = blockIdx.x >> 4;
    int t = blockIdx.x & 15;
    int which = threadIdx.x >> 6;
    int d = threadIdx.x & 63;
    const float* W = which ? Wv_w : Wk_w;
    const float* bias = which ? Wv_b : Wk_b;
    const float4* row = (const float4*)(gt + (size_t)(b * 16 + t) * 1024);
    const float4* wr = (const float4*)(W + (size_t)d * 1024);
    float acc = 0.f;
    for (int c = 0; c < 256; ++c) {
        float4 a = row[c], w = wr[c];
        acc += a.x * w.x; acc += a.y * w.y; acc += a.z * w.z; acc += a.w * w.w;
    }
    int i2 = d >> 1;
    float dv = expf((float)(2 * i2) * (-0.14391156831212787f)); // -ln(10000)/64
    float ang = (float)t * dv;
    float pe = (d & 1) ? cosf(ang) : sinf(ang);
    KtVt[((size_t)(b * 2 + which) * 16 + t) * 64 + d] = acc + bias[d] + pe;
}

// ---------------------------------------------------------------------------
// token prep 2 (per graph): k/v head proj; V2 = out_w-folded v heads into LDS;
// emits Mfold[g][th=t*4+h][4] and v2f[g] (V2^T, bf16 A-frag layout).
// ---------------------------------------------------------------------------
__global__ __launch_bounds__(256)
void k_tokens2(const float* __restrict__ KtVt,
               const float* __restrict__ in_proj_w, const float* __restrict__ in_proj_b,
               const float* __restrict__ out_w,
               const float* __restrict__ Wq_w, const float* __restrict__ Wq_b,
               float* __restrict__ Mfold, uint4* __restrict__ v2fG)
{
    int b = blockIdx.x;
    int tid = threadIdx.x;
    __shared__ float KtL[1024], VtL[1024], vv[1024], kproj[1024];
    __shared__ float v2L[4096];
    __shared__ float qWs[192], qbs[64];
    for (int idx = tid; idx < 1024; idx += 256) {
        KtL[idx] = KtVt[(size_t)(b * 2 + 0) * 1024 + idx];
        VtL[idx] = KtVt[(size_t)(b * 2 + 1) * 1024 + idx];
    }
    __syncthreads();
    for (int idx = tid; idx < 2048; idx += 256) {
        int which = idx >> 10; int td = idx & 1023; int t = td >> 6; int j = td & 63;
        int r = (which ? 128 : 64) + j;
        const float* w = in_proj_w + (size_t)r * 64;
        const float* src = which ? VtL : KtL;
        float acc = in_proj_b[r];
#pragma unroll 8
        for (int dd = 0; dd < 64; ++dd) acc += src[t * 64 + dd] * w[dd];
        if (which) vv[t * 64 + j] = acc;
        else kproj[t * 64 + j] = acc;
    }
    for (int idx = tid; idx < 192; idx += 256) {
        int c = idx >> 6; int j = idx & 63;
        float acc = 0.f;
        for (int dd = 0; dd < 64; ++dd) acc += in_proj_w[(size_t)j * 64 + dd] * Wq_w[dd * 3 + c];
        qWs[c * 64 + j] = acc;
    }
    for (int j = tid; j < 64; j += 256) {
        float acc = in_proj_b[j];
        for (int dd = 0; dd < 64; ++dd) acc += in_proj_w[(size_t)j * 64 + dd] * Wq_b[dd];
        qbs[j] = acc;
    }
    __syncthreads();
    for (int idx = tid; idx < 4096; idx += 256) {
        int jo = idx & 63; int th2 = idx >> 6; int h = th2 & 3; int t = th2 >> 2;
        float acc = 0.f;
#pragma unroll
        for (int dd = 0; dd < 16; ++dd)
            acc += vv[t * 64 + h * 16 + dd] * out_w[(size_t)jo * 64 + h * 16 + dd];
        v2L[(t * 4 + h) * 64 + jo] = acc;
    }
    {
        int th = tid >> 2, c = tid & 3;
        int t = th >> 2, h = th & 3;
        float acc = 0.f;
#pragma unroll
        for (int dd = h * 16; dd < h * 16 + 16; ++dd) {
            float w = (c == 0) ? qWs[dd] : (c == 1) ? qWs[64 + dd]
                    : (c == 2) ? qWs[128 + dd] : qbs[dd];
            acc += w * kproj[t * 64 + dd];
        }
        Mfold[((size_t)b * 64 + th) * 4 + c] = 0.25f * acc;
    }
    __syncthreads();
    for (int it = tid; it < 512; it += 256) {
        int lane = it & 63, fi = it >> 6;
        int mi = fi >> 1, step = fi & 1;
        int outd = mi * 16 + (lane & 15);
        int th0 = step * 32 + (lane >> 4) * 8;
        uint4 v;
        v.x = f2b_pack(v2L[(th0 + 0) * 64 + outd], v2L[(th0 + 1) * 64 + outd]);
        v.y = f2b_pack(v2L[(th0 + 2) * 64 + outd], v2L[(th0 + 3) * 64 + outd]);
        v.z = f2b_pack(v2L[(th0 + 4) * 64 + outd], v2L[(th0 + 5) * 64 + outd]);
        v.w = f2b_pack(v2L[(th0 + 6) * 64 + outd], v2L[(th0 + 7) * 64 + outd]);
        v2fG[((size_t)b * 8 + fi) * 64 + lane] = v;
    }
}

// ---------------------------------------------------------------------------
// per-edge cross attention, MFMA PV. __expf kept (not implicated by R10
// counters; softmax renormalizes so ULP delta washes out).
// ---------------------------------------------------------------------------
__global__ __launch_bounds__(256)
void k_edge_attn(const float* __restrict__ ps, const int* __restrict__ ei,
                 const float* __restrict__ Mfold, const uint4* __restrict__ v2f,
                 const float* __restrict__ ob,
                 unsigned short* __restrict__ Pf, float* __restrict__ cnt)
{
    __shared__ unsigned attL[4 * 64 * 34];     // 34.8 KB; per-wave 64x34-dword slab
    int tid = threadIdx.x;
    int wave = tid >> 6, lane = tid & 63, q = lane >> 4, c15 = lane & 15;
    int g = blockIdx.x >> 7;                   // 128 blocks per graph
    int e = blockIdx.x * 256 + tid;
    int s = ei[e], d = ei[EE + e];
    atomicAdd(&cnt[d], 1.f);
    float sx = ps[s * 3], sy = ps[s * 3 + 1], sz = ps[s * 3 + 2];
    float dx = ps[d * 3], dy = ps[d * 3 + 1], dz = ps[d * 3 + 2];
    float px = dx - sx, py = dy - sy, pz = dz - sz;
    float ex = 0.5f * (dx + sx), ey = 0.5f * (dy + sy), ez = 0.5f * (dz + sz);

    const float4* Mg = (const float4*)Mfold + (size_t)g * 64;
    float sc[64];
#pragma unroll
    for (int th = 0; th < 64; ++th) {
        float4 m = Mg[th];
        sc[th] = ex * m.x + ey * m.y + ez * m.z + m.w;
    }
#pragma unroll
    for (int h = 0; h < 4; ++h) {
        float mx = sc[h];
#pragma unroll
        for (int t = 1; t < 16; ++t) mx = fmaxf(mx, sc[t * 4 + h]);
        float ssum = 0.f;
#pragma unroll
        for (int t = 0; t < 16; ++t) {
            float eo = __expf(sc[t * 4 + h] - mx);
            sc[t * 4 + h] = eo; ssum += eo;
        }
        float inv = 1.f / ssum;
#pragma unroll
        for (int t = 0; t < 16; ++t) sc[t * 4 + h] *= inv;
    }
    unsigned* slab = attL + wave * 64 * 34;
#pragma unroll
    for (int k = 0; k < 16; ++k) {
        uint2 v;
        v.x = f2b_pack(sc[4 * k + 0], sc[4 * k + 1]);
        v.y = f2b_pack(sc[4 * k + 2], sc[4 * k + 3]);
        *(uint2*)&slab[lane * 34 + 2 * k] = v;
    }
    __syncthreads();

    uint4 v2a[4][2];
#pragma unroll
    for (int mi = 0; mi < 4; ++mi)
#pragma unroll
        for (int st = 0; st < 2; ++st)
            v2a[mi][st] = v2f[((size_t)g * 8 + mi * 2 + st) * 64 + lane];

    f32x4 acc[4][4];
#pragma unroll
    for (int mi = 0; mi < 4; ++mi)
#pragma unroll
        for (int nt = 0; nt < 4; ++nt) acc[mi][nt] = (f32x4){0.f, 0.f, 0.f, 0.f};

#pragma unroll
    for (int nt = 0; nt < 4; ++nt) {
        const unsigned* rb = &slab[(nt * 16 + c15) * 34];
        uint4 b0 = *(const uint4*)&rb[q * 4];
        uint4 b1 = *(const uint4*)&rb[16 + q * 4];
#pragma unroll
        for (int mi = 0; mi < 4; ++mi) {
            acc[mi][nt] = __builtin_amdgcn_mfma_f32_16x16x32_bf16(bc8(v2a[mi][0]), bc8(b0), acc[mi][nt], 0, 0, 0);
            acc[mi][nt] = __builtin_amdgcn_mfma_f32_16x16x32_bf16(bc8(v2a[mi][1]), bc8(b1), acc[mi][nt], 0, 0, 0);
        }
    }
    __syncthreads();

    float4 obv[4];
#pragma unroll
    for (int mi = 0; mi < 4; ++mi) obv[mi] = *(const float4*)(ob + mi * 16 + q * 4);
#pragma unroll
    for (int mi = 0; mi < 4; ++mi)
#pragma unroll
        for (int nt = 0; nt < 4; ++nt) {
            f32x4 a = acc[mi][nt];
            uint2 v;
            v.x = f2b_pack(a[0] + obv[mi].x, a[1] + obv[mi].y);
            v.y = f2b_pack(a[2] + obv[mi].z, a[3] + obv[mi].w);
            *(uint2*)&slab[(nt * 16 + c15) * 34 + mi * 8 + q * 2] = v;
        }
    __syncthreads();

    uint4* Pf4 = (uint4*)Pf;
#pragma unroll
    for (int et = 0; et < 4; ++et) {
        int etg = blockIdx.x * 16 + wave * 4 + et;
#pragma unroll
        for (int st = 0; st < 2; ++st) {
            uint4 w = *(const uint4*)&slab[(et * 16 + c15) * 34 + st * 16 + q * 4];
            Pf4[((size_t)etg * 3 + st) * 64 + lane] = w;
        }
    }
    int et2 = e >> 4, eL = e & 15;
    size_t tb = ((size_t)(et2 * 3 + 2) * 64 + 0 * 16 + eL) * 8;
    uint2 t0; t0.x = f2b_pack(px, py); t0.y = f2b_pack(pz, 1.0f);
    *(uint2*)(Pf + tb) = t0;
    uint2 z2; z2.x = 0u; z2.y = 0u;
    *(uint2*)(Pf + tb + 4) = z2;
#pragma unroll
    for (int quad = 1; quad < 4; ++quad) {
        size_t zb = ((size_t)(et2 * 3 + 2) * 64 + quad * 16 + eL) * 8;
        uint4 z4; z4.x = 0u; z4.y = 0u; z4.z = 0u; z4.w = 0u;
        *(uint4*)(Pf + zb) = z4;
    }
}

// ---------------------------------------------------------------------------
// fused repack of all 3 layers' nn_w/nn_b -> bf16 B-fragment streams
// ---------------------------------------------------------------------------
static __device__ inline void repack_one(const float* __restrict__ nw,
                                         const float* __restrict__ nb,
                                         unsigned short* __restrict__ Wf, int idx)
{
    int jj = idx & 7;
    int lane = (idx >> 3) & 63;
    int rest = idx >> 9;
    int s = rest % 3;
    int jt = rest / 3;
    int j = jt * 16 + (lane & 15);
    int k = s * 32 + (lane >> 4) * 8 + jj;
    float v;
    if (k < 64)       v = nw[(size_t)j * 67 + 3 + k];
    else if (k < 67)  v = nw[(size_t)j * 67 + (k - 64)];
    else if (k == 67) v = nb[j];
    else              v = 0.f;
    Wf[idx] = f2b(v);
}

__global__ __launch_bounds__(256)
void k_repackAll(const float* __restrict__ nw0, const float* __restrict__ nb0,
                 const float* __restrict__ nw1, const float* __restrict__ nb1,
                 const float* __restrict__ nw2, const float* __restrict__ nb2,
                 unsigned short* __restrict__ Wf0, unsigned short* __restrict__ Wf1,
                 unsigned short* __restrict__ Wf2)
{
    int idx = blockIdx.x * 256 + threadIdx.x;
    if (idx < 98304)        repack_one(nw0, nb0, Wf0, idx);
    else if (idx < 196608)  repack_one(nw1, nb1, Wf1, idx - 98304);
    else                    repack_one(nw2, nb2, Wf2, idx - 196608);
}

// ---------------------------------------------------------------------------
// MFMA edge pass, split-K wave pairs — EXACT R4 body (128 edges/block, grid
// 1024, 4 blocks/CU). NO unroll pragma: R10 proved +unroll2 spills to
// scratch (FETCH 21->183MB, WRITE 16->122MB). 6/6 perturbations of this
// kernel regressed; the R4 register/LDS/grid balance is the local optimum.
// ---------------------------------------------------------------------------
template<int CO>
__global__ __launch_bounds__(256, 4)
void k_conv_mfma(const uint4* __restrict__ Pf, const float* __restrict__ hin,
                 const int* __restrict__ ei, const uint4* __restrict__ Wf,
                 float* __restrict__ aggr)
{
    __shared__ float hL[128 * 36];             // 18.4 KB
    __shared__ int sL[128];
    __shared__ int dL[128];
    constexpr int REDSZ = (CO == 16) ? 2 * 64 * 17 : 4;
    __shared__ float red[REDSZ];               // 8.7 KB (CO=16 only)

    int tid = threadIdx.x;
    int e0 = blockIdx.x * 128;
    if (tid < 128) sL[tid] = ei[e0 + tid];
    else           dL[tid - 128] = ei[EE + e0 + (tid - 128)];
    __syncthreads();
    for (int idx = tid; idx < 1024; idx += 256) {
        int row = idx >> 3, c = idx & 7;
        const float4* hr = (const float4*)(hin + (size_t)sL[row] * 32);
        *(float4*)&hL[row * 36 + c * 4] = hr[c];
    }
    __syncthreads();

    int wave = tid >> 6, lane = tid & 63, quad = lane >> 4, col = lane & 15;
    int group = wave >> 1, half = wave & 1;

    uint4 a[4][3];
    int et0 = blockIdx.x * 8 + group * 4;
#pragma unroll
    for (int st = 0; st < 4; ++st)
#pragma unroll
        for (int s = 0; s < 3; ++s)
            a[st][s] = Pf[((size_t)(et0 + st) * 3 + s) * 64 + lane];

    float msg[4][4];
#pragma unroll
    for (int st = 0; st < 4; ++st)
#pragma unroll
        for (int r = 0; r < 4; ++r) msg[st][r] = 0.f;

    int ibase = (CO == 32) ? 0 : half * 16;
    constexpr int NI2 = (CO == 32) ? 16 : 8;   // i-pairs per wave

    for (int i2 = 0; i2 < NI2; ++i2) {
        float2 hv2[4][4];
#pragma unroll
        for (int st = 0; st < 4; ++st)
#pragma unroll
            for (int r = 0; r < 4; ++r)
                hv2[st][r] = *(const float2*)&hL[(group * 64 + st * 16 + quad * 4 + r) * 36
                                                 + ibase + i2 * 2];
#pragma unroll
        for (int ii = 0; ii < 2; ++ii) {
            int i = ibase + i2 * 2 + ii;
            int jt = (CO == 32) ? (i * 2 + half) : i;
            uint4 b0 = Wf[((size_t)jt * 3 + 0) * 64 + lane];
            uint4 b1 = Wf[((size_t)jt * 3 + 1) * 64 + lane];
            uint4 b2 = Wf[((size_t)jt * 3 + 2) * 64 + lane];
#pragma unroll
            for (int st = 0; st < 4; ++st) {
                f32x4 c = {0.f, 0.f, 0.f, 0.f};
                c = __builtin_amdgcn_mfma_f32_16x16x32_bf16(bc8(a[st][0]), bc8(b0), c, 0, 0, 0);
                c = __builtin_amdgcn_mfma_f32_16x16x32_bf16(bc8(a[st][1]), bc8(b1), c, 0, 0, 0);
                c = __builtin_amdgcn_mfma_f32_16x16x32_bf16(bc8(a[st][2]), bc8(b2), c, 0, 0, 0);
#pragma unroll
                for (int r = 0; r < 4; ++r) {
                    float hv = ii ? hv2[st][r].y : hv2[st][r].x;
                    msg[st][r] += hv * fmaxf(c[r], 0.f);
                }
            }
        }
    }

    if (CO == 32) {
#pragma unroll
        for (int st = 0; st < 4; ++st)
#pragma unroll
            for (int r = 0; r < 4; ++r) {
                int dv = dL[group * 64 + st * 16 + quad * 4 + r];
                atomicAdd(&aggr[(size_t)dv * 32 + half * 16 + col], msg[st][r]);
            }
    } else {
        if (half == 1) {
#pragma unroll
            for (int st = 0; st < 4; ++st)
#pragma unroll
                for (int r = 0; r < 4; ++r)
                    red[group * 64 * 17 + lane * 17 + st * 4 + r] = msg[st][r];
        }
        __syncthreads();
        if (half == 0) {
#pragma unroll
            for (int st = 0; st < 4; ++st)
#pragma unroll
                for (int r = 0; r < 4; ++r) {
                    float m = msg[st][r] + red[group * 64 * 17 + lane * 17 + st * 4 + r];
                    int dv = dL[group * 64 + st * 16 + quad * 4 + r];
                    atomicAdd(&aggr[(size_t)dv * 16 + col], m);
                }
        }
    }
}

// ---------------------------------------------------------------------------
// node update: h' = relu(aggr/cnt + h @ root + bias); zeroes aggr for the
// next layer's atomic pass. hr reads vectorized to float4 (kept; not
// implicated by R10 counters).
// ---------------------------------------------------------------------------
template<int CO>
__global__ __launch_bounds__(256)
void k_update(float* __restrict__ aggr, const float* __restrict__ cnt,
              const float* __restrict__ hin, const float* __restrict__ root,
              const float* __restrict__ bias, float* __restrict__ hout)
{
    __shared__ float rL[32 * CO];
    __shared__ float bL[CO];
    int tid = threadIdx.x;
    for (int idx = tid; idx < 32 * CO; idx += 256) rL[idx] = root[idx];
    if (tid < CO) bL[tid] = bias[tid];
    __syncthreads();
    int gid = blockIdx.x * 256 + tid;
    int v = gid / CO;
    int o = gid % CO;
    float acc = aggr[gid] / fmaxf(cnt[v], 1.f) + bL[o];
    aggr[gid] = 0.f;                    // prep next layer's scatter
    const float4* hr4 = (const float4*)(hin + (size_t)v * 32);
#pragma unroll
    for (int i4 = 0; i4 < 8; ++i4) {
        float4 hv = hr4[i4];
        acc += hv.x * rL[(i4 * 4 + 0) * CO + o];
        acc += hv.y * rL[(i4 * 4 + 1) * CO + o];
        acc += hv.z * rL[(i4 * 4 + 2) * CO + o];
        acc += hv.w * rL[(i4 * 4 + 3) * CO + o];
    }
    hout[gid] = fmaxf(acc, 0.f);
}

// ---------------------------------------------------------------------------
extern "C" void kernel_launch(void* const* d_in, const int* in_sizes, int n_in,
                              void* d_out, int out_size, void* d_ws, size_t ws_size,
                              hipStream_t stream)
{
    const float* x          = (const float*)d_in[0];
    const float* pos        = (const float*)d_in[1];
    const float* x_skip     = (const float*)d_in[3];
    const float* pos_skip   = (const float*)d_in[4];
    const int*   batch_skip = (const int*)  d_in[5];
    const int*   ei         = (const int*)  d_in[6];
    const float* gt         = (const float*)d_in[7];
    const float* Wq_w       = (const float*)d_in[8];
    const float* Wq_b       = (const float*)d_in[9];
    const float* Wk_w       = (const float*)d_in[10];
    const float* Wk_b       = (const float*)d_in[11];
    const float* Wv_w       = (const float*)d_in[12];
    const float* Wv_b       = (const float*)d_in[13];
    const float* in_proj_w  = (const float*)d_in[14];
    const float* in_proj_b  = (const float*)d_in[15];
    const float* out_w      = (const float*)d_in[16];
    const float* out_b      = (const float*)d_in[17];
    const float* nn_w0 = (const float*)d_in[18]; const float* nn_b0 = (const float*)d_in[19];
    const float* root0 = (const float*)d_in[20]; const float* bias0 = (const float*)d_in[21];
    const float* nn_w1 = (const float*)d_in[22]; const float* nn_b1 = (const float*)d_in[23];
    const float* root1 = (const float*)d_in[24]; const float* bias1 = (const float*)d_in[25];
    const float* nn_w2 = (const float*)d_in[26]; const float* nn_b2 = (const float*)d_in[27];
    const float* root2 = (const float*)d_in[28]; const float* bias2 = (const float*)d_in[29];

    char* wsb = (char*)d_ws;
    size_t off = 0;
    auto carve = [&](size_t bytes) { char* p = wsb + off; off += (bytes + 255) & ~(size_t)255; return p; };
    float* aggr = (float*)carve((size_t)MM * 32 * 4);   // aggr then cnt: one memset
    float* cnt  = (float*)carve((size_t)MM * 4);
    float* hA   = (float*)carve((size_t)MM * 32 * 4);
    float* hB   = (float*)carve((size_t)MM * 32 * 4);
    unsigned short* Pf  = (unsigned short*)carve((size_t)EE * 96 * 2);
    unsigned short* Wf0 = (unsigned short*)carve((size_t)1024 * 96 * 2);
    unsigned short* Wf1 = (unsigned short*)carve((size_t)1024 * 96 * 2);
    unsigned short* Wf2 = (unsigned short*)carve((size_t)512 * 96 * 2);
    float* Mfold = (float*)carve((size_t)NB * 64 * 4 * 4);
    uint4* v2f   = (uint4*)carve((size_t)NB * 8 * 64 * 16);
    float* KtVt  = (float*)carve((size_t)NB * 2 * 16 * 64 * 4);

    float* h_final   = (float*)d_out;                 // [M,16]
    float* out_pos   = (float*)d_out + (size_t)MM * 16;
    float* out_batch = (float*)d_out + (size_t)MM * 19;

    // one memset covers aggr (MM*32) + cnt (MM) — adjacent carves
    hipMemsetAsync(aggr, 0, ((size_t)MM * 32 + MM) * sizeof(float), stream);

    k_knn<<<MM / 128, 512, 0, stream>>>(pos, pos_skip, x, x_skip, batch_skip,
                                        hA, out_pos, out_batch);
    k_tokens1<<<64, 128, 0, stream>>>(gt, Wk_w, Wk_b, Wv_w, Wv_b, KtVt);
    k_tokens2<<<NB, 256, 0, stream>>>(KtVt, in_proj_w, in_proj_b, out_w, Wq_w, Wq_b,
                                      Mfold, v2f);
    k_edge_attn<<<EE / 256, 256, 0, stream>>>(pos_skip, ei, Mfold, v2f, out_b,
                                              Pf, cnt);
    k_repackAll<<<960, 256, 0, stream>>>(nn_w0, nn_b0, nn_w1, nn_b1, nn_w2, nn_b2,
                                         Wf0, Wf1, Wf2);

    // layer 0: hA -> hB   (update zeroes aggr for layer 1)
    k_conv_mfma<32><<<EE / 128, 256, 0, stream>>>((const uint4*)Pf, hA, ei, (const uint4*)Wf0, aggr);
    k_update<32><<<(MM * 32) / 256, 256, 0, stream>>>(aggr, cnt, hA, root0, bias0, hB);
    // layer 1: hB -> hA   (update zeroes aggr for layer 2)
    k_conv_mfma<32><<<EE / 128, 256, 0, stream>>>((const uint4*)Pf, hB, ei, (const uint4*)Wf1, aggr);
    k_update<32><<<(MM * 32) / 256, 256, 0, stream>>>(aggr, cnt, hB, root1, bias1, hA);
    // layer 2: hA -> d_out
    k_conv_mfma<16><<<EE / 128, 256, 0, stream>>>((const uint4*)Pf, hA, ei, (const uint4*)Wf2, aggr);
    k_update<16><<<(MM * 16) / 256, 256, 0, stream>>>(aggr, cnt, hA, root2, bias2, h_final);
}